// Round 4
// baseline (269.944 us; speedup 1.0000x reference)
//
#include <hip/hip_runtime.h>
#include <hip/hip_bf16.h>

#define SLEN 4096
#define DH 768
#define NHEAD 12
#define DA 64

using short8 = __attribute__((ext_vector_type(8))) short;
using f32x4  = __attribute__((ext_vector_type(4))) float;

static __device__ __forceinline__ unsigned short f2b(float f) {
    union { __hip_bfloat16 h; unsigned short u; } c;
    c.h = __float2bfloat16(f);
    return c.u;
}

static __device__ __forceinline__ unsigned pkbf(float a, float b) {
    __hip_bfloat162 h = __float22bfloat162_rn(float2{a, b});
    union { __hip_bfloat162 h; unsigned u; } c; c.h = h; return c.u;
}

// native 2^x — single v_exp_f32, no libcall fallback
static __device__ __forceinline__ float fexp2(float x) {
    float r; asm("v_exp_f32 %0, %1" : "=v"(r) : "v"(x)); return r;
}

// {a,b} -> a'={a.lo,b.lo}, b'={a.hi,b.hi}  (swap across lane^32)
static __device__ __forceinline__ void swap32(unsigned& a, unsigned& b, int g1) {
#if __has_builtin(__builtin_amdgcn_permlane32_swap)
    typedef unsigned uv2 __attribute__((ext_vector_type(2)));
    uv2 r = __builtin_amdgcn_permlane32_swap(a, b, false, false);
    a = r.x; b = r.y;
#else
    unsigned own = g1 ? b : a, send = g1 ? a : b;
    unsigned recv = __shfl_xor(send, 32);
    unsigned nlo = g1 ? recv : own;
    unsigned nhi = g1 ? own : recv;
    a = nlo; b = nhi;
#endif
}

// {a,b} -> a'={a.q0,b.q0,a.q2,b.q2}, b'={a.q1,b.q1,a.q3,b.q3}  (swap across lane^16)
static __device__ __forceinline__ void swap16(unsigned& a, unsigned& b, int g0) {
#if __has_builtin(__builtin_amdgcn_permlane16_swap)
    typedef unsigned uv2 __attribute__((ext_vector_type(2)));
    uv2 r = __builtin_amdgcn_permlane16_swap(a, b, false, false);
    a = r.x; b = r.y;
#else
    unsigned own = g0 ? b : a, send = g0 ? a : b;
    unsigned recv = __shfl_xor(send, 16);
    unsigned nlo = g0 ? recv : own;
    unsigned nhi = g0 ? own : recv;
    a = nlo; b = nhi;
#endif
}

#define GLD_LDS16(gp, lp) __builtin_amdgcn_global_load_lds( \
    (const __attribute__((address_space(1))) unsigned int*)(gp), \
    (__attribute__((address_space(3))) unsigned int*)(lp), 16, 0, 0)

#define CSCALE 0.18033688011f   // 0.125 * log2(e)

// ------- merged: 4x weight transpose+cvt, plus mask -> log2-domain bias expand -------
__global__ __launch_bounds__(256) void wtrans4(const float* __restrict__ w_v, const float* __restrict__ w_k,
                                               const float* __restrict__ w_q, const float* __restrict__ w_o,
                                               unsigned short* __restrict__ WtV, unsigned short* __restrict__ WtK,
                                               unsigned short* __restrict__ WtQ, unsigned short* __restrict__ WtO,
                                               const int* __restrict__ mask, float* __restrict__ biasE) {
    const int z = blockIdx.y;
    const int t = threadIdx.x;
    if (z == 4) {
        int i = blockIdx.x * 256 + t;
        if (i < 2 * SLEN) biasE[i] = -1.442695041e9f * (float)mask[i];
        return;
    }
    const float* W = (z == 0) ? w_v : (z == 1) ? w_k : (z == 2) ? w_q : w_o;
    unsigned short* Wt = (z == 0) ? WtV : (z == 1) ? WtK : (z == 2) ? WtQ : WtO;
    __shared__ float tile[64][65];
    const int tk = blockIdx.x / 12, tn = blockIdx.x % 12;
    const int k0 = tk * 64, n0 = tn * 64;
#pragma unroll
    for (int i = 0; i < 4; ++i) {
        int uid = t + 256 * i;
        int r = uid >> 4, c = (uid & 15) * 4;
        float4 v4 = *reinterpret_cast<const float4*>(W + (size_t)(k0 + r) * DH + n0 + c);
        tile[r][c] = v4.x; tile[r][c + 1] = v4.y; tile[r][c + 2] = v4.z; tile[r][c + 3] = v4.w;
    }
    __syncthreads();
#pragma unroll
    for (int i = 0; i < 2; ++i) {
        int uid = t + 256 * i;
        int n = uid >> 3, c = (uid & 7) * 8;
        union { unsigned short us[8]; uint4 u; } pk;
#pragma unroll
        for (int j = 0; j < 8; ++j) pk.us[j] = f2b(tile[c + j][n]);
        *reinterpret_cast<uint4*>(Wt + (size_t)(n0 + n) * DH + k0 + c) = pk.u;
    }
}

// ---- fused QKV projection. z=0: V -> VhT (pre-transposed). z=1: K. z=2: Q (pre-scaled) ----
__global__ __launch_bounds__(256) void proj3(const float* __restrict__ vin, const float* __restrict__ kin,
                                             const float* __restrict__ qin,
                                             const unsigned short* __restrict__ WtV,
                                             const unsigned short* __restrict__ WtK,
                                             const unsigned short* __restrict__ WtQ,
                                             unsigned short* __restrict__ VhT,
                                             unsigned short* __restrict__ Kh,
                                             unsigned short* __restrict__ Qh) {
    __shared__ unsigned char shraw[17408];
    unsigned short (*As)[40] = reinterpret_cast<unsigned short(*)[40]>(shraw);          // 128x40
    unsigned short (*Bs)[40] = reinterpret_cast<unsigned short(*)[40]>(shraw + 10240);  // 64x40
    const int t = threadIdx.x;
    const int w = t >> 6, lane = t & 63, lr = lane & 15, lg = lane >> 4;
    const int zz = blockIdx.y;
    const int z = zz / 12, h = zz % 12;
    const float* X = (z == 0) ? vin : (z == 1) ? kin : qin;
    const unsigned short* Wt = (z == 0) ? WtV : (z == 1) ? WtK : WtQ;
    const int row0 = blockIdx.x * 128;
    const int n0 = h * 64;
    f32x4 acc[2][4] = {};
    for (int kt = 0; kt < 24; ++kt) {
        const int k0 = kt * 32;
#pragma unroll
        for (int i = 0; i < 4; ++i) {
            int r = (t >> 3) + 32 * i;
            int c = (t & 7) * 4;
            float4 v4 = *reinterpret_cast<const float4*>(X + (size_t)(row0 + r) * DH + k0 + c);
            uint2 pk;
            pk.x = pkbf(v4.x, v4.y);
            pk.y = pkbf(v4.z, v4.w);
            *reinterpret_cast<uint2*>(&As[r][c]) = pk;
        }
        {
            int n = t >> 2, c = (t & 3) * 8;
            *reinterpret_cast<uint4*>(&Bs[n][c]) =
                *reinterpret_cast<const uint4*>(Wt + (size_t)(n0 + n) * DH + k0 + c);
        }
        __syncthreads();
        short8 af[2], bf[4];
#pragma unroll
        for (int mi = 0; mi < 2; ++mi)
            af[mi] = *reinterpret_cast<const short8*>(&As[w * 32 + mi * 16 + lr][lg * 8]);
#pragma unroll
        for (int ni = 0; ni < 4; ++ni)
            bf[ni] = *reinterpret_cast<const short8*>(&Bs[ni * 16 + lr][lg * 8]);
#pragma unroll
        for (int mi = 0; mi < 2; ++mi)
#pragma unroll
            for (int ni = 0; ni < 4; ++ni)
                acc[mi][ni] = __builtin_amdgcn_mfma_f32_16x16x32_bf16(af[mi], bf[ni], acc[mi][ni], 0, 0, 0);
        __syncthreads();
    }
    const int b = row0 >> 12, s0 = row0 & 4095;
    if (z == 0) {
        // V: bounce through LDS to write VhT[bh][d][s] coalesced along s
        unsigned short (*Vt_e)[136] = reinterpret_cast<unsigned short(*)[136]>(shraw);
#pragma unroll
        for (int mi = 0; mi < 2; ++mi)
#pragma unroll
            for (int ni = 0; ni < 4; ++ni) {
                int d = ni * 16 + lr, sl = w * 32 + mi * 16 + lg * 4;
                *reinterpret_cast<unsigned*>(&Vt_e[d][sl])     = pkbf(acc[mi][ni][0], acc[mi][ni][1]);
                *reinterpret_cast<unsigned*>(&Vt_e[d][sl + 2]) = pkbf(acc[mi][ni][2], acc[mi][ni][3]);
            }
        __syncthreads();
        int d = t >> 2, sc = (t & 3) * 32;
        unsigned short* dst = VhT + ((size_t)(b * NHEAD + h) * DA + d) * SLEN + s0 + sc;
#pragma unroll
        for (int c = 0; c < 4; ++c)
            *reinterpret_cast<uint4*>(dst + c * 8) = *reinterpret_cast<const uint4*>(&Vt_e[d][sc + c * 8]);
    } else {
        unsigned short* Y = (z == 1) ? Kh : Qh;
        const float scale = (z == 2) ? CSCALE : 1.0f;
#pragma unroll
        for (int mi = 0; mi < 2; ++mi)
#pragma unroll
            for (int ni = 0; ni < 4; ++ni)
#pragma unroll
                for (int r = 0; r < 4; ++r) {
                    int s = s0 + w * 32 + mi * 16 + lg * 4 + r;
                    int d = ni * 16 + lr;
                    Y[(size_t)((b * NHEAD + h) * SLEN + s) * DA + d] = f2b(acc[mi][ni][r] * scale);
                }
    }
}

// ---------------- flash attention (swapped-QK^T, in-register softmax, QBLK=64) ----
__global__ __launch_bounds__(256, 5) void attn_kernel(const unsigned short* __restrict__ Qh,
                                                      const unsigned short* __restrict__ Kh,
                                                      const unsigned short* __restrict__ VhT,
                                                      const float* __restrict__ biasE,
                                                      unsigned short* __restrict__ AT) {
    __shared__ unsigned smem4[8192];   // 32 KB: [K0 8K][V0 8K][K1 8K][V1 8K]; epilogue reuse

    const int t = threadIdx.x;
    const int w = t >> 6, lane = t & 63, lr = lane & 15, lg = lane >> 4;
    const int g0 = (lane >> 4) & 1, g1 = (lane >> 5) & 1;
    const int lr7 = lr & 7;

    // bijective XCD swizzle: 3 heads per XCD, all 64 q-blocks of a head on one XCD
    const int i = blockIdx.x;          // 0..1535
    const int bh = (i & 7) * 3 + ((i >> 3) >> 6);
    const int qb = (i >> 3) & 63;
    const int b = bh / NHEAD;
    const int q0 = qb * 64;
    const size_t base = (size_t)bh * SLEN * DA;
    const int wq0 = q0 + w * 16;

    short8 qf[2];
#pragma unroll
    for (int ks = 0; ks < 2; ++ks)
        qf[ks] = *reinterpret_cast<const short8*>(
            Qh + base + (size_t)(wq0 + lr) * DA + ks * 32 + lg * 8);

    // lane-constant staging offsets (linear LDS dest, XOR-pre-swizzled global source)
    const int uid0 = (w << 6) | lane, uid1 = ((4 + w) << 6) | lane;
    const int r0 = uid0 >> 3, r1 = uid1 >> 3;
    const int sc0 = ((uid0 & 7) ^ (r0 & 7)) * 8, sc1 = ((uid1 & 7) ^ (r1 & 7)) * 8;
    const size_t kofs0 = base + (size_t)r0 * DA + sc0;
    const size_t kofs1 = base + (size_t)r1 * DA + sc1;
    const size_t vofs0 = ((size_t)bh * DA + r0) * SLEN + sc0;
    const size_t vofs1 = ((size_t)bh * DA + r1) * SLEN + sc1;
    const float* biasB = biasE + b * SLEN;

#define STAGE(KT, PAR) do {                                                         \
        size_t koff_ = (size_t)(KT) * 64 * DA; int vcol_ = (KT) * 64;               \
        char* lb_ = (char*)smem4 + (PAR) * 16384;                                   \
        GLD_LDS16(Kh + kofs0 + koff_, lb_ + w * 1024);                              \
        GLD_LDS16(Kh + kofs1 + koff_, lb_ + (4 + w) * 1024);                        \
        GLD_LDS16(VhT + vofs0 + vcol_, lb_ + 8192 + w * 1024);                      \
        GLD_LDS16(VhT + vofs1 + vcol_, lb_ + 8192 + (4 + w) * 1024);                \
    } while (0)

    float m_ = -1e30f, l_ = 0.f;
    f32x4 oacc[4] = {};

    STAGE(0, 0);
    __syncthreads();

    for (int kt = 0; kt < 64; ++kt) {
        const int par = kt & 1;
        const int kk0 = kt * 64;
        if (kt < 63) STAGE(kt + 1, par ^ 1);

        const unsigned short (*Ks)[64] =
            (const unsigned short(*)[64])((const char*)smem4 + par * 16384);
        const unsigned short (*Vt)[64] =
            (const unsigned short(*)[64])((const char*)smem4 + par * 16384 + 8192);

        f32x4 bias4[4];
#pragma unroll
        for (int ni = 0; ni < 4; ++ni)
            bias4[ni] = *reinterpret_cast<const f32x4*>(biasB + kk0 + ni * 16 + lg * 4);

        // S^T = K Q^T : out col = q(=lr), row = key  (Q pre-scaled by 0.125*log2e)
        f32x4 st[4] = {};
        __builtin_amdgcn_s_setprio(1);
#pragma unroll
        for (int ks = 0; ks < 2; ++ks)
#pragma unroll
            for (int ni = 0; ni < 4; ++ni) {
                int slot = (ks * 4 + lg) ^ lr7;
                short8 kf = *reinterpret_cast<const short8*>(&Ks[ni * 16 + lr][slot * 8]);
                st[ni] = __builtin_amdgcn_mfma_f32_16x16x32_bf16(kf, qf[ks], st[ni], 0, 0, 0);
            }
        __builtin_amdgcn_s_setprio(0);

#pragma unroll
        for (int ni = 0; ni < 4; ++ni)
            st[ni] = st[ni] + bias4[ni];

        // row max via max3-shaped tree (8 ops, depth 3) + 2 cross-lane steps
        float a0 = fmaxf(fmaxf(st[0][0], st[0][1]), st[0][2]);
        float a1 = fmaxf(fmaxf(st[0][3], st[1][0]), st[1][1]);
        float a2 = fmaxf(fmaxf(st[1][2], st[1][3]), st[2][0]);
        float a3 = fmaxf(fmaxf(st[2][1], st[2][2]), st[2][3]);
        float a4 = fmaxf(fmaxf(st[3][0], st[3][1]), st[3][2]);
        float vmx = fmaxf(fmaxf(fmaxf(a0, a1), a2), fmaxf(fmaxf(a3, a4), st[3][3]));
        vmx = fmaxf(vmx, __shfl_xor(vmx, 16));
        vmx = fmaxf(vmx, __shfl_xor(vmx, 32));

        // defer-max (T13, THR=8 in log2 domain)
        if (__any(vmx > m_ + 8.f)) {
            float mn = fmaxf(m_, vmx);
            float sc = fexp2(m_ - mn);
            m_ = mn;
            l_ *= sc;
#pragma unroll
            for (int ni = 0; ni < 4; ++ni) oacc[ni] *= sc;
        }

        // P = 2^(S - m); lane-local l partial
        unsigned D[8];
        float lsum = 0.f;
#pragma unroll
        for (int ni = 0; ni < 4; ++ni) {
            float p0 = fexp2(st[ni][0] - m_);
            float p1 = fexp2(st[ni][1] - m_);
            float p2 = fexp2(st[ni][2] - m_);
            float p3 = fexp2(st[ni][3] - m_);
            lsum += (p0 + p1) + (p2 + p3);
            D[ni * 2]     = pkbf(p0, p1);
            D[ni * 2 + 1] = pkbf(p2, p3);
        }
        l_ += lsum;

        // in-register P transpose via permlane swaps (T12)
#pragma unroll
        for (int p4 = 0; p4 < 2; ++p4)
#pragma unroll
            for (int p0b = 0; p0b < 2; ++p0b)
                swap32(D[4 * p4 + p0b], D[4 * p4 + 2 + p0b], g1);
#pragma unroll
        for (int p4 = 0; p4 < 2; ++p4)
#pragma unroll
            for (int p0b = 0; p0b < 2; ++p0b)
                swap16(D[4 * p4 + p0b], D[4 * p4 + 2 + p0b], g0);
        union { unsigned u[4]; short8 s; } pa0, pa1;
        pa0.u[0] = D[0]; pa0.u[1] = D[1]; pa0.u[2] = D[2]; pa0.u[3] = D[3];
        pa1.u[0] = D[4]; pa1.u[1] = D[5]; pa1.u[2] = D[6]; pa1.u[7 - 7] = pa1.u[0]; // no-op guard
        pa1.u[0] = D[4]; pa1.u[1] = D[5]; pa1.u[2] = D[6]; pa1.u[3] = D[7];

        // O^T += V^T P^T : out col = q(=lr), row = d
        __builtin_amdgcn_s_setprio(1);
#pragma unroll
        for (int ni = 0; ni < 4; ++ni) {
            int row = ni * 16 + lr;
            int slot0 = lg ^ lr7;
            int slot1 = (4 + lg) ^ lr7;
            short8 vf0 = *reinterpret_cast<const short8*>(&Vt[row][slot0 * 8]);
            short8 vf1 = *reinterpret_cast<const short8*>(&Vt[row][slot1 * 8]);
            oacc[ni] = __builtin_amdgcn_mfma_f32_16x16x32_bf16(vf0, pa0.s, oacc[ni], 0, 0, 0);
            oacc[ni] = __builtin_amdgcn_mfma_f32_16x16x32_bf16(vf1, pa1.s, oacc[ni], 0, 0, 0);
        }
        __builtin_amdgcn_s_setprio(0);
        __syncthreads();
    }
#undef STAGE

    // epilogue: finish l, O^T -> per-wave LDS bounce -> coalesced row-major store
    {
        float l = l_;
        l += __shfl_xor(l, 16);
        l += __shfl_xor(l, 32);
        float inv = 1.0f / l;
        unsigned* Obw = smem4 + w * (16 * 36);
#pragma unroll
        for (int ni = 0; ni < 4; ++ni) {
            uint2 pr;
            pr.x = pkbf(oacc[ni][0] * inv, oacc[ni][1] * inv);
            pr.y = pkbf(oacc[ni][2] * inv, oacc[ni][3] * inv);
            *reinterpret_cast<uint2*>(&Obw[lr * 36 + ni * 8 + lg * 2]) = pr;
        }
        int row = lane >> 2, q4 = lane & 3;
        int qg = q0 + w * 16 + row;
        unsigned short* dst = AT + (size_t)(b * SLEN + qg) * DH + (bh % NHEAD) * DA + q4 * 16;
#pragma unroll
        for (int c = 0; c < 2; ++c) {
            uint4 v = *reinterpret_cast<const uint4*>(&Obw[row * 36 + q4 * 8 + c * 4]);
            *reinterpret_cast<uint4*>(dst + c * 8) = v;
        }
    }
}

// ---------------- output projection: out(fp32) = AT(bf16) @ Wt_o^T + b_o ----
__global__ __launch_bounds__(256) void proj_out(const unsigned short* __restrict__ X,
                                                const unsigned short* __restrict__ Wt,
                                                const float* __restrict__ bias,
                                                float* __restrict__ Y) {
    __shared__ unsigned short As[128][40];
    __shared__ unsigned short Bs[64][40];
    const int t = threadIdx.x;
    const int w = t >> 6, lane = t & 63, lr = lane & 15, lg = lane >> 4;
    const int row0 = blockIdx.x * 128;
    const int n0 = blockIdx.y * 64;
    f32x4 acc[2][4] = {};
    for (int kt = 0; kt < 24; ++kt) {
        const int k0 = kt * 32;
#pragma unroll
        for (int i = 0; i < 2; ++i) {
            int uid = t + 256 * i;
            int r = uid >> 2, c = (uid & 3) * 8;
            *reinterpret_cast<uint4*>(&As[r][c]) =
                *reinterpret_cast<const uint4*>(X + (size_t)(row0 + r) * DH + k0 + c);
        }
        {
            int n = t >> 2, c = (t & 3) * 8;
            *reinterpret_cast<uint4*>(&Bs[n][c]) =
                *reinterpret_cast<const uint4*>(Wt + (size_t)(n0 + n) * DH + k0 + c);
        }
        __syncthreads();
        short8 af[2], bf[4];
#pragma unroll
        for (int mi = 0; mi < 2; ++mi)
            af[mi] = *reinterpret_cast<const short8*>(&As[w * 32 + mi * 16 + lr][lg * 8]);
#pragma unroll
        for (int ni = 0; ni < 4; ++ni)
            bf[ni] = *reinterpret_cast<const short8*>(&Bs[ni * 16 + lr][lg * 8]);
#pragma unroll
        for (int mi = 0; mi < 2; ++mi)
#pragma unroll
            for (int ni = 0; ni < 4; ++ni)
                acc[mi][ni] = __builtin_amdgcn_mfma_f32_16x16x32_bf16(af[mi], bf[ni], acc[mi][ni], 0, 0, 0);
        __syncthreads();
    }
#pragma unroll
    for (int ni = 0; ni < 4; ++ni) {
        float bv = bias[n0 + ni * 16 + lr];
#pragma unroll
        for (int mi = 0; mi < 2; ++mi)
#pragma unroll
            for (int r = 0; r < 4; ++r) {
                int row = row0 + w * 32 + mi * 16 + lg * 4 + r;
                Y[(size_t)row * DH + n0 + ni * 16 + lr] = acc[mi][ni][r] + bv;
            }
    }
}

extern "C" void kernel_launch(void* const* d_in, const int* in_sizes, int n_in,
                              void* d_out, int out_size, void* d_ws, size_t ws_size,
                              hipStream_t stream) {
    const float* v   = (const float*)d_in[0];
    const float* k   = (const float*)d_in[1];
    const float* q   = (const float*)d_in[2];
    const int*  mask = (const int*)d_in[3];
    const float* w_v = (const float*)d_in[4];
    const float* w_k = (const float*)d_in[5];
    const float* w_q = (const float*)d_in[6];
    const float* w_o = (const float*)d_in[7];
    const float* b_o = (const float*)d_in[8];
    float* out = (float*)d_out;

    char* ws = (char*)d_ws;
    unsigned short* Qh  = (unsigned short*)(ws);                 // 12.58 MB
    unsigned short* Kh  = (unsigned short*)(ws + 12582912);
    unsigned short* AT  = (unsigned short*)(ws + 25165824);
    unsigned short* VhT = (unsigned short*)(ws + 37748736);
    unsigned short* WtV = (unsigned short*)(ws + 50331648);
    unsigned short* WtK = WtV + 589824;
    unsigned short* WtQ = WtK + 589824;
    unsigned short* WtO = WtQ + 589824;
    float* biasE = (float*)(ws + 55050240);                      // 32 KB

    wtrans4<<<dim3(144, 5), 256, 0, stream>>>(w_v, w_k, w_q, w_o, WtV, WtK, WtQ, WtO, mask, biasE);
    proj3<<<dim3(64, 36), 256, 0, stream>>>(v, k, q, WtV, WtK, WtQ, VhT, Kh, Qh);
    attn_kernel<<<1536, 256, 0, stream>>>(Qh, Kh, VhT, biasE, AT);
    proj_out<<<dim3(64, 12), 256, 0, stream>>>(AT, WtO, b_o, out);
}

// Round 5
// 236.491 us; speedup vs baseline: 1.1415x; 1.1415x over previous
//
#include <hip/hip_runtime.h>
#include <hip/hip_bf16.h>

#define SLEN 4096
#define DH 768
#define NHEAD 12
#define DA 64

using short8 = __attribute__((ext_vector_type(8))) short;
using f32x4  = __attribute__((ext_vector_type(4))) float;
typedef unsigned uv2 __attribute__((ext_vector_type(2)));

static __device__ __forceinline__ unsigned short f2b(float f) {
    union { __hip_bfloat16 h; unsigned short u; } c;
    c.h = __float2bfloat16(f);
    return c.u;
}

static __device__ __forceinline__ unsigned pkbf(float a, float b) {
    __hip_bfloat162 h = __float22bfloat162_rn(float2{a, b});
    union { __hip_bfloat162 h; unsigned u; } c; c.h = h; return c.u;
}

// native 2^x — single v_exp_f32, no libcall fallback
static __device__ __forceinline__ float fexp2(float x) {
    float r; asm("v_exp_f32 %0, %1" : "=v"(r) : "v"(x)); return r;
}

// {a,b} -> a'={a.lo,b.lo}, b'={a.hi,b.hi}  (swap across lane^32)
static __device__ __forceinline__ void swap32(unsigned& a, unsigned& b, int g1) {
#if __has_builtin(__builtin_amdgcn_permlane32_swap)
    uv2 r = __builtin_amdgcn_permlane32_swap(a, b, false, false);
    a = r.x; b = r.y;
#else
    unsigned own = g1 ? b : a, send = g1 ? a : b;
    unsigned recv = __shfl_xor(send, 32);
    unsigned nlo = g1 ? recv : own;
    unsigned nhi = g1 ? own : recv;
    a = nlo; b = nhi;
#endif
}

// {a,b} -> a'={a.q0,b.q0,a.q2,b.q2}, b'={a.q1,b.q1,a.q3,b.q3}  (swap across lane^16)
static __device__ __forceinline__ void swap16(unsigned& a, unsigned& b, int g0) {
#if __has_builtin(__builtin_amdgcn_permlane16_swap)
    uv2 r = __builtin_amdgcn_permlane16_swap(a, b, false, false);
    a = r.x; b = r.y;
#else
    unsigned own = g0 ? b : a, send = g0 ? a : b;
    unsigned recv = __shfl_xor(send, 16);
    unsigned nlo = g0 ? recv : own;
    unsigned nhi = g0 ? own : recv;
    a = nlo; b = nhi;
#endif
}

static __device__ __forceinline__ float crossmax16(float v) {
#if __has_builtin(__builtin_amdgcn_permlane16_swap)
    uv2 r = __builtin_amdgcn_permlane16_swap(__float_as_uint(v), __float_as_uint(v), false, false);
    return fmaxf(__uint_as_float(r.x), __uint_as_float(r.y));
#else
    return fmaxf(v, __shfl_xor(v, 16));
#endif
}

static __device__ __forceinline__ float crossmax32(float v) {
#if __has_builtin(__builtin_amdgcn_permlane32_swap)
    uv2 r = __builtin_amdgcn_permlane32_swap(__float_as_uint(v), __float_as_uint(v), false, false);
    return fmaxf(__uint_as_float(r.x), __uint_as_float(r.y));
#else
    return fmaxf(v, __shfl_xor(v, 32));
#endif
}

#define GLD_LDS16(gp, lp) __builtin_amdgcn_global_load_lds( \
    (const __attribute__((address_space(1))) unsigned int*)(gp), \
    (__attribute__((address_space(3))) unsigned int*)(lp), 16, 0, 0)

#define CSCALE 0.18033688011f   // 0.125 * log2(e)

// ------- merged: 4x weight transpose+cvt, plus mask -> log2-domain bias expand -------
__global__ __launch_bounds__(256) void wtrans4(const float* __restrict__ w_v, const float* __restrict__ w_k,
                                               const float* __restrict__ w_q, const float* __restrict__ w_o,
                                               unsigned short* __restrict__ WtV, unsigned short* __restrict__ WtK,
                                               unsigned short* __restrict__ WtQ, unsigned short* __restrict__ WtO,
                                               const int* __restrict__ mask, float* __restrict__ biasE) {
    const int z = blockIdx.y;
    const int t = threadIdx.x;
    if (z == 4) {
        int i = blockIdx.x * 256 + t;
        if (i < 2 * SLEN) biasE[i] = -1.442695041e9f * (float)mask[i];
        return;
    }
    const float* W = (z == 0) ? w_v : (z == 1) ? w_k : (z == 2) ? w_q : w_o;
    unsigned short* Wt = (z == 0) ? WtV : (z == 1) ? WtK : (z == 2) ? WtQ : WtO;
    __shared__ float tile[64][65];
    const int tk = blockIdx.x / 12, tn = blockIdx.x % 12;
    const int k0 = tk * 64, n0 = tn * 64;
#pragma unroll
    for (int i = 0; i < 4; ++i) {
        int uid = t + 256 * i;
        int r = uid >> 4, c = (uid & 15) * 4;
        float4 v4 = *reinterpret_cast<const float4*>(W + (size_t)(k0 + r) * DH + n0 + c);
        tile[r][c] = v4.x; tile[r][c + 1] = v4.y; tile[r][c + 2] = v4.z; tile[r][c + 3] = v4.w;
    }
    __syncthreads();
#pragma unroll
    for (int i = 0; i < 2; ++i) {
        int uid = t + 256 * i;
        int n = uid >> 3, c = (uid & 7) * 8;
        union { unsigned short us[8]; uint4 u; } pk;
#pragma unroll
        for (int j = 0; j < 8; ++j) pk.us[j] = f2b(tile[c + j][n]);
        *reinterpret_cast<uint4*>(Wt + (size_t)(n0 + n) * DH + k0 + c) = pk.u;
    }
}

// ---- fused QKV projection. z=0: V -> VhT (pre-transposed). z=1: K. z=2: Q (pre-scaled) ----
__global__ __launch_bounds__(256) void proj3(const float* __restrict__ vin, const float* __restrict__ kin,
                                             const float* __restrict__ qin,
                                             const unsigned short* __restrict__ WtV,
                                             const unsigned short* __restrict__ WtK,
                                             const unsigned short* __restrict__ WtQ,
                                             unsigned short* __restrict__ VhT,
                                             unsigned short* __restrict__ Kh,
                                             unsigned short* __restrict__ Qh) {
    __shared__ unsigned char shraw[17408];
    unsigned short (*As)[40] = reinterpret_cast<unsigned short(*)[40]>(shraw);          // 128x40
    unsigned short (*Bs)[40] = reinterpret_cast<unsigned short(*)[40]>(shraw + 10240);  // 64x40
    const int t = threadIdx.x;
    const int w = t >> 6, lane = t & 63, lr = lane & 15, lg = lane >> 4;
    const int zz = blockIdx.y;
    const int z = zz / 12, h = zz % 12;
    const float* X = (z == 0) ? vin : (z == 1) ? kin : qin;
    const unsigned short* Wt = (z == 0) ? WtV : (z == 1) ? WtK : WtQ;
    const int row0 = blockIdx.x * 128;
    const int n0 = h * 64;
    f32x4 acc[2][4] = {};
    for (int kt = 0; kt < 24; ++kt) {
        const int k0 = kt * 32;
#pragma unroll
        for (int i = 0; i < 4; ++i) {
            int r = (t >> 3) + 32 * i;
            int c = (t & 7) * 4;
            float4 v4 = *reinterpret_cast<const float4*>(X + (size_t)(row0 + r) * DH + k0 + c);
            uint2 pk;
            pk.x = pkbf(v4.x, v4.y);
            pk.y = pkbf(v4.z, v4.w);
            *reinterpret_cast<uint2*>(&As[r][c]) = pk;
        }
        {
            int n = t >> 2, c = (t & 3) * 8;
            *reinterpret_cast<uint4*>(&Bs[n][c]) =
                *reinterpret_cast<const uint4*>(Wt + (size_t)(n0 + n) * DH + k0 + c);
        }
        __syncthreads();
        short8 af[2], bf[4];
#pragma unroll
        for (int mi = 0; mi < 2; ++mi)
            af[mi] = *reinterpret_cast<const short8*>(&As[w * 32 + mi * 16 + lr][lg * 8]);
#pragma unroll
        for (int ni = 0; ni < 4; ++ni)
            bf[ni] = *reinterpret_cast<const short8*>(&Bs[ni * 16 + lr][lg * 8]);
#pragma unroll
        for (int mi = 0; mi < 2; ++mi)
#pragma unroll
            for (int ni = 0; ni < 4; ++ni)
                acc[mi][ni] = __builtin_amdgcn_mfma_f32_16x16x32_bf16(af[mi], bf[ni], acc[mi][ni], 0, 0, 0);
        __syncthreads();
    }
    const int b = row0 >> 12, s0 = row0 & 4095;
    if (z == 0) {
        // V: bounce through LDS to write VhT[bh][d][s] coalesced along s
        unsigned short (*Vt_e)[136] = reinterpret_cast<unsigned short(*)[136]>(shraw);
#pragma unroll
        for (int mi = 0; mi < 2; ++mi)
#pragma unroll
            for (int ni = 0; ni < 4; ++ni) {
                int d = ni * 16 + lr, sl = w * 32 + mi * 16 + lg * 4;
                *reinterpret_cast<unsigned*>(&Vt_e[d][sl])     = pkbf(acc[mi][ni][0], acc[mi][ni][1]);
                *reinterpret_cast<unsigned*>(&Vt_e[d][sl + 2]) = pkbf(acc[mi][ni][2], acc[mi][ni][3]);
            }
        __syncthreads();
        int d = t >> 2, sc = (t & 3) * 32;
        unsigned short* dst = VhT + ((size_t)(b * NHEAD + h) * DA + d) * SLEN + s0 + sc;
#pragma unroll
        for (int c = 0; c < 4; ++c)
            *reinterpret_cast<uint4*>(dst + c * 8) = *reinterpret_cast<const uint4*>(&Vt_e[d][sc + c * 8]);
    } else {
        unsigned short* Y = (z == 1) ? Kh : Qh;
        const float scale = (z == 2) ? CSCALE : 1.0f;
#pragma unroll
        for (int mi = 0; mi < 2; ++mi)
#pragma unroll
            for (int ni = 0; ni < 4; ++ni)
#pragma unroll
                for (int r = 0; r < 4; ++r) {
                    int s = s0 + w * 32 + mi * 16 + lg * 4 + r;
                    int d = ni * 16 + lr;
                    Y[(size_t)((b * NHEAD + h) * SLEN + s) * DA + d] = f2b(acc[mi][ni][r] * scale);
                }
    }
}

// ---------------- flash attention: QBLK=128, ring-3 LDS, software-pipelined ----------------
__global__ __launch_bounds__(256, 3) void attn_kernel(const unsigned short* __restrict__ Qh,
                                                      const unsigned short* __restrict__ Kh,
                                                      const unsigned short* __restrict__ VhT,
                                                      const float* __restrict__ biasE,
                                                      unsigned short* __restrict__ AT) {
    __shared__ __align__(16) char smem[49152];   // 3 x (K 8KB + V 8KB); epilogue reuse at +16384
    const int t = threadIdx.x;
    const int w = t >> 6, lane = t & 63, lr = lane & 15, lg = lane >> 4;
    const int g0 = (lane >> 4) & 1, g1 = (lane >> 5) & 1;
    const int lr7 = lr & 7;

    // bijective XCD swizzle: 3 heads per XCD, all 32 q-blocks of a head on one XCD
    const int i = blockIdx.x;          // 0..767
    const int bh = (i & 7) * 3 + ((i >> 3) >> 5);
    const int qb = (i >> 3) & 31;
    const int b = bh / NHEAD;
    const int q0 = qb * 128;
    const size_t base = (size_t)bh * SLEN * DA;
    const int wq0 = q0 + w * 32;

    short8 qf[2][2];
#pragma unroll
    for (int mi = 0; mi < 2; ++mi)
#pragma unroll
        for (int ks = 0; ks < 2; ++ks)
            qf[mi][ks] = *reinterpret_cast<const short8*>(
                Qh + base + (size_t)(wq0 + mi * 16 + lr) * DA + ks * 32 + lg * 8);

    // staging source (pre-XOR-swizzled global, linear LDS dest); advance by one tile per STAGE
    const int uid0 = (w << 6) | lane;
    const int r0 = uid0 >> 3;
    const int sc0 = ((uid0 & 7) ^ (r0 & 7)) * 8;
    const unsigned short* kp = Kh + base + (size_t)r0 * DA + sc0;
    const unsigned short* vp = VhT + ((size_t)bh * DA + r0) * SLEN + sc0;
    const float* bp = biasE + b * SLEN + lg * 4;

    // ds_read lane addresses (byte offsets within a buffer); all reads use imm offsets off these
    const int a0 = lr * 128 + ((lg) ^ lr7) * 16;
    const int a1 = lr * 128 + ((4 + lg) ^ lr7) * 16;

    float m_[2] = {-1e30f, -1e30f};
    f32x4 st[2][4];
    f32x4 oacc[2][4] = {};
    f32x4 oacc_l[2] = {};
    f32x4 bias_c[4];
    short8 pa[2][2];
    union { unsigned u[4]; short8 s; } ones;
    ones.u[0] = 0x3F803F80u; ones.u[1] = 0x3F803F80u; ones.u[2] = 0x3F803F80u; ones.u[3] = 0x3F803F80u;

#define STAGE(CB) do {                                                   \
        GLD_LDS16(kp,              smem + (CB) + w * 1024);              \
        GLD_LDS16(kp + 2048,       smem + (CB) + (4 + w) * 1024);        \
        GLD_LDS16(vp,              smem + (CB) + 8192 + w * 1024);       \
        GLD_LDS16(vp + 32 * SLEN,  smem + (CB) + 8192 + (4 + w) * 1024); \
        kp += 64 * DA; vp += 64;                                         \
    } while (0)

#define BIASLD do {                                                              \
        _Pragma("unroll") for (int ni = 0; ni < 4; ++ni)                         \
            bias_c[ni] = *reinterpret_cast<const f32x4*>(bp + ni * 16);          \
        bp += 64;                                                                \
    } while (0)

#define QKT(NB) do {                                                                           \
        _Pragma("unroll") for (int ni = 0; ni < 4; ++ni) {                                     \
            short8 kf0 = *reinterpret_cast<const short8*>(smem + (NB) + ni * 2048 + a0);       \
            short8 kf1 = *reinterpret_cast<const short8*>(smem + (NB) + ni * 2048 + a1);       \
            st[0][ni] = __builtin_amdgcn_mfma_f32_16x16x32_bf16(kf1, qf[0][1],                 \
                        __builtin_amdgcn_mfma_f32_16x16x32_bf16(kf0, qf[0][0], bias_c[ni], 0, 0, 0), 0, 0, 0); \
            st[1][ni] = __builtin_amdgcn_mfma_f32_16x16x32_bf16(kf1, qf[1][1],                 \
                        __builtin_amdgcn_mfma_f32_16x16x32_bf16(kf0, qf[1][0], bias_c[ni], 0, 0, 0), 0, 0, 0); \
        }                                                                                      \
    } while (0)

#define PV(CB) do {                                                                                  \
        _Pragma("unroll") for (int ni = 0; ni < 4; ++ni) {                                           \
            short8 vf0 = *reinterpret_cast<const short8*>(smem + (CB) + 8192 + ni * 2048 + a0);      \
            short8 vf1 = *reinterpret_cast<const short8*>(smem + (CB) + 8192 + ni * 2048 + a1);      \
            oacc[0][ni] = __builtin_amdgcn_mfma_f32_16x16x32_bf16(vf0, pa[0][0], oacc[0][ni], 0, 0, 0); \
            oacc[0][ni] = __builtin_amdgcn_mfma_f32_16x16x32_bf16(vf1, pa[0][1], oacc[0][ni], 0, 0, 0); \
            oacc[1][ni] = __builtin_amdgcn_mfma_f32_16x16x32_bf16(vf0, pa[1][0], oacc[1][ni], 0, 0, 0); \
            oacc[1][ni] = __builtin_amdgcn_mfma_f32_16x16x32_bf16(vf1, pa[1][1], oacc[1][ni], 0, 0, 0); \
        }                                                                                            \
        oacc_l[0] = __builtin_amdgcn_mfma_f32_16x16x32_bf16(ones.s, pa[0][0], oacc_l[0], 0, 0, 0);   \
        oacc_l[0] = __builtin_amdgcn_mfma_f32_16x16x32_bf16(ones.s, pa[0][1], oacc_l[0], 0, 0, 0);   \
        oacc_l[1] = __builtin_amdgcn_mfma_f32_16x16x32_bf16(ones.s, pa[1][0], oacc_l[1], 0, 0, 0);   \
        oacc_l[1] = __builtin_amdgcn_mfma_f32_16x16x32_bf16(ones.s, pa[1][1], oacc_l[1], 0, 0, 0);   \
    } while (0)

#define SOFTMAX do {                                                                               \
        float rmax[2];                                                                             \
        _Pragma("unroll") for (int mi = 0; mi < 2; ++mi) {                                         \
            float m3a = fmaxf(fmaxf(st[mi][0][0], st[mi][0][1]), st[mi][0][2]);                    \
            float m3b = fmaxf(fmaxf(st[mi][0][3], st[mi][1][0]), st[mi][1][1]);                    \
            float m3c = fmaxf(fmaxf(st[mi][1][2], st[mi][1][3]), st[mi][2][0]);                    \
            float m3d = fmaxf(fmaxf(st[mi][2][1], st[mi][2][2]), st[mi][2][3]);                    \
            float m3e = fmaxf(fmaxf(st[mi][3][0], st[mi][3][1]), st[mi][3][2]);                    \
            float vv = fmaxf(fmaxf(fmaxf(m3a, m3b), m3c), fmaxf(fmaxf(m3d, m3e), st[mi][3][3]));   \
            vv = crossmax16(vv);                                                                   \
            vv = crossmax32(vv);                                                                   \
            rmax[mi] = vv;                                                                         \
        }                                                                                          \
        if (__any((rmax[0] > m_[0] + 8.f) | (rmax[1] > m_[1] + 8.f))) {                            \
            float mn0 = fmaxf(m_[0], rmax[0]), mn1 = fmaxf(m_[1], rmax[1]);                        \
            float sc0f = fexp2(m_[0] - mn0), sc1f = fexp2(m_[1] - mn1);                            \
            m_[0] = mn0; m_[1] = mn1;                                                              \
            _Pragma("unroll") for (int ni = 0; ni < 4; ++ni) { oacc[0][ni] *= sc0f; oacc[1][ni] *= sc1f; } \
            oacc_l[0] *= sc0f; oacc_l[1] *= sc1f;                                                  \
        }                                                                                          \
        _Pragma("unroll") for (int mi = 0; mi < 2; ++mi) {                                         \
            unsigned D[8];                                                                         \
            _Pragma("unroll") for (int ni = 0; ni < 4; ++ni) {                                     \
                float p0 = fexp2(st[mi][ni][0] - m_[mi]);                                          \
                float p1 = fexp2(st[mi][ni][1] - m_[mi]);                                          \
                float p2 = fexp2(st[mi][ni][2] - m_[mi]);                                          \
                float p3 = fexp2(st[mi][ni][3] - m_[mi]);                                          \
                D[ni * 2] = pkbf(p0, p1);                                                          \
                D[ni * 2 + 1] = pkbf(p2, p3);                                                      \
            }                                                                                      \
            swap32(D[0], D[2], g1); swap32(D[1], D[3], g1);                                        \
            swap32(D[4], D[6], g1); swap32(D[5], D[7], g1);                                        \
            swap16(D[0], D[2], g0); swap16(D[1], D[3], g0);                                        \
            swap16(D[4], D[6], g0); swap16(D[5], D[7], g0);                                        \
            union { unsigned u[4]; short8 s; } c0, c1;                                             \
            c0.u[0] = D[0]; c0.u[1] = D[1]; c0.u[2] = D[2]; c0.u[3] = D[3];                        \
            c1.u[0] = D[4]; c1.u[1] = D[5]; c1.u[2] = D[6]; c1.u[3] = D[7];                        \
            pa[mi][0] = c0.s; pa[mi][1] = c1.s;                                                    \
        }                                                                                          \
    } while (0)

#define BODY(KT, CB, NB, NNB) do {                                       \
        BIASLD;                        /* bias for tile KT+1 */          \
        SOFTMAX;                                                         \
        __syncthreads();                                                 \
        if ((KT) < 62) STAGE(NNB);                                       \
        __builtin_amdgcn_s_setprio(1);                                   \
        QKT(NB);                                                         \
        PV(CB);                                                          \
        __builtin_amdgcn_s_setprio(0);                                   \
    } while (0)

    // prologue: tiles 0,1 staged; bias(0); QK^T(0)
    STAGE(0);
    __syncthreads();
    BIASLD;
    STAGE(16384);
    __builtin_amdgcn_s_setprio(1);
    QKT(0);
    __builtin_amdgcn_s_setprio(0);

    for (int it = 0; it < 21; ++it) {
        BODY(3 * it,     0,     16384, 32768);
        BODY(3 * it + 1, 16384, 32768, 0);
        BODY(3 * it + 2, 32768, 0,     16384);
    }
    // final tile kt=63 (in buffer 0): no stage, no next-QKT
    SOFTMAX;
    __syncthreads();
    __builtin_amdgcn_s_setprio(1);
    PV(0);
    __builtin_amdgcn_s_setprio(0);

#undef BODY
#undef SOFTMAX
#undef PV
#undef QKT
#undef BIASLD
#undef STAGE

    // epilogue: l from ones-row accumulator (all entries equal), LDS bounce, coalesced store
    {
        float inv[2];
        inv[0] = 1.0f / oacc_l[0][0];
        inv[1] = 1.0f / oacc_l[1][0];
        unsigned* Obw = reinterpret_cast<unsigned*>(smem + 16384) + w * (32 * 36);
#pragma unroll
        for (int mi = 0; mi < 2; ++mi)
#pragma unroll
            for (int ni = 0; ni < 4; ++ni) {
                uint2 pr;
                pr.x = pkbf(oacc[mi][ni][0] * inv[mi], oacc[mi][ni][1] * inv[mi]);
                pr.y = pkbf(oacc[mi][ni][2] * inv[mi], oacc[mi][ni][3] * inv[mi]);
                *reinterpret_cast<uint2*>(&Obw[(mi * 16 + lr) * 36 + ni * 8 + lg * 2]) = pr;
            }
        int row = lane >> 1, half = lane & 1;
        int qg = q0 + w * 32 + row;
        unsigned short* dst = AT + (size_t)(b * SLEN + qg) * DH + (bh % NHEAD) * DA + half * 32;
#pragma unroll
        for (int c = 0; c < 4; ++c) {
            uint4 v = *reinterpret_cast<const uint4*>(&Obw[row * 36 + half * 16 + c * 4]);
            *reinterpret_cast<uint4*>(dst + c * 8) = v;
        }
    }
}

// ---------------- output projection: out(fp32) = AT(bf16) @ Wt_o^T + b_o ----
__global__ __launch_bounds__(256) void proj_out(const unsigned short* __restrict__ X,
                                                const unsigned short* __restrict__ Wt,
                                                const float* __restrict__ bias,
                                                float* __restrict__ Y) {
    __shared__ unsigned short As[128][40];
    __shared__ unsigned short Bs[64][40];
    const int t = threadIdx.x;
    const int w = t >> 6, lane = t & 63, lr = lane & 15, lg = lane >> 4;
    const int row0 = blockIdx.x * 128;
    const int n0 = blockIdx.y * 64;
    f32x4 acc[2][4] = {};
    for (int kt = 0; kt < 24; ++kt) {
        const int k0 = kt * 32;
#pragma unroll
        for (int i = 0; i < 2; ++i) {
            int uid = t + 256 * i;
            int r = uid >> 2, c = (uid & 3) * 8;
            *reinterpret_cast<uint4*>(&As[r][c]) =
                *reinterpret_cast<const uint4*>(X + (size_t)(row0 + r) * DH + k0 + c);
        }
        {
            int n = t >> 2, c = (t & 3) * 8;
            *reinterpret_cast<uint4*>(&Bs[n][c]) =
                *reinterpret_cast<const uint4*>(Wt + (size_t)(n0 + n) * DH + k0 + c);
        }
        __syncthreads();
        short8 af[2], bf[4];
#pragma unroll
        for (int mi = 0; mi < 2; ++mi)
            af[mi] = *reinterpret_cast<const short8*>(&As[w * 32 + mi * 16 + lr][lg * 8]);
#pragma unroll
        for (int ni = 0; ni < 4; ++ni)
            bf[ni] = *reinterpret_cast<const short8*>(&Bs[ni * 16 + lr][lg * 8]);
#pragma unroll
        for (int mi = 0; mi < 2; ++mi)
#pragma unroll
            for (int ni = 0; ni < 4; ++ni)
                acc[mi][ni] = __builtin_amdgcn_mfma_f32_16x16x32_bf16(af[mi], bf[ni], acc[mi][ni], 0, 0, 0);
        __syncthreads();
    }
#pragma unroll
    for (int ni = 0; ni < 4; ++ni) {
        float bv = bias[n0 + ni * 16 + lr];
#pragma unroll
        for (int mi = 0; mi < 2; ++mi)
#pragma unroll
            for (int r = 0; r < 4; ++r) {
                int row = row0 + w * 32 + mi * 16 + lg * 4 + r;
                Y[(size_t)row * DH + n0 + ni * 16 + lr] = acc[mi][ni][r] + bv;
            }
    }
}

extern "C" void kernel_launch(void* const* d_in, const int* in_sizes, int n_in,
                              void* d_out, int out_size, void* d_ws, size_t ws_size,
                              hipStream_t stream) {
    const float* v   = (const float*)d_in[0];
    const float* k   = (const float*)d_in[1];
    const float* q   = (const float*)d_in[2];
    const int*  mask = (const int*)d_in[3];
    const float* w_v = (const float*)d_in[4];
    const float* w_k = (const float*)d_in[5];
    const float* w_q = (const float*)d_in[6];
    const float* w_o = (const float*)d_in[7];
    const float* b_o = (const float*)d_in[8];
    float* out = (float*)d_out;

    char* ws = (char*)d_ws;
    unsigned short* Qh  = (unsigned short*)(ws);                 // 12.58 MB
    unsigned short* Kh  = (unsigned short*)(ws + 12582912);
    unsigned short* AT  = (unsigned short*)(ws + 25165824);
    unsigned short* VhT = (unsigned short*)(ws + 37748736);
    unsigned short* WtV = (unsigned short*)(ws + 50331648);
    unsigned short* WtK = WtV + 589824;
    unsigned short* WtQ = WtK + 589824;
    unsigned short* WtO = WtQ + 589824;
    float* biasE = (float*)(ws + 55050240);                      // 32 KB

    wtrans4<<<dim3(144, 5), 256, 0, stream>>>(w_v, w_k, w_q, w_o, WtV, WtK, WtQ, WtO, mask, biasE);
    proj3<<<dim3(64, 36), 256, 0, stream>>>(v, k, q, WtV, WtK, WtQ, VhT, Kh, Qh);
    attn_kernel<<<768, 256, 0, stream>>>(Qh, Kh, VhT, biasE, AT);
    proj_out<<<dim3(64, 12), 256, 0, stream>>>(AT, WtO, b_o, out);
}

// Round 6
// 227.752 us; speedup vs baseline: 1.1853x; 1.0384x over previous
//
#include <hip/hip_runtime.h>
#include <hip/hip_bf16.h>

#define SLEN 4096
#define DH 768
#define NHEAD 12
#define DA 64

using short8 = __attribute__((ext_vector_type(8))) short;
using f32x4  = __attribute__((ext_vector_type(4))) float;
typedef unsigned uv2 __attribute__((ext_vector_type(2)));

static __device__ __forceinline__ unsigned short f2b(float f) {
    union { __hip_bfloat16 h; unsigned short u; } c;
    c.h = __float2bfloat16(f);
    return c.u;
}

static __device__ __forceinline__ unsigned pkbf(float a, float b) {
    __hip_bfloat162 h = __float22bfloat162_rn(float2{a, b});
    union { __hip_bfloat162 h; unsigned u; } c; c.h = h; return c.u;
}

// native 2^x — single v_exp_f32, no libcall fallback
static __device__ __forceinline__ float fexp2(float x) {
    float r; asm("v_exp_f32 %0, %1" : "=v"(r) : "v"(x)); return r;
}

// {a,b} -> a'={a.lo,b.lo}, b'={a.hi,b.hi}  (swap across lane^32)
static __device__ __forceinline__ void swap32(unsigned& a, unsigned& b, int g1) {
#if __has_builtin(__builtin_amdgcn_permlane32_swap)
    uv2 r = __builtin_amdgcn_permlane32_swap(a, b, false, false);
    a = r.x; b = r.y;
#else
    unsigned own = g1 ? b : a, send = g1 ? a : b;
    unsigned recv = __shfl_xor(send, 32);
    unsigned nlo = g1 ? recv : own;
    unsigned nhi = g1 ? own : recv;
    a = nlo; b = nhi;
#endif
}

// {a,b} -> a'={a.q0,b.q0,a.q2,b.q2}, b'={a.q1,b.q1,a.q3,b.q3}  (swap across lane^16)
static __device__ __forceinline__ void swap16(unsigned& a, unsigned& b, int g0) {
#if __has_builtin(__builtin_amdgcn_permlane16_swap)
    uv2 r = __builtin_amdgcn_permlane16_swap(a, b, false, false);
    a = r.x; b = r.y;
#else
    unsigned own = g0 ? b : a, send = g0 ? a : b;
    unsigned recv = __shfl_xor(send, 16);
    unsigned nlo = g0 ? recv : own;
    unsigned nhi = g0 ? own : recv;
    a = nlo; b = nhi;
#endif
}

#define GLD_LDS16(gp, lp) __builtin_amdgcn_global_load_lds( \
    (const __attribute__((address_space(1))) unsigned int*)(gp), \
    (__attribute__((address_space(3))) unsigned int*)(lp), 16, 0, 0)

#define CSCALE 0.18033688011f   // 0.125 * log2(e)

// ------- merged: 4x weight transpose+cvt, plus mask -> log2-domain bias expand -------
__global__ __launch_bounds__(256) void wtrans4(const float* __restrict__ w_v, const float* __restrict__ w_k,
                                               const float* __restrict__ w_q, const float* __restrict__ w_o,
                                               unsigned short* __restrict__ WtV, unsigned short* __restrict__ WtK,
                                               unsigned short* __restrict__ WtQ, unsigned short* __restrict__ WtO,
                                               const int* __restrict__ mask, float* __restrict__ biasE) {
    const int z = blockIdx.y;
    const int t = threadIdx.x;
    if (z == 4) {
        int i = blockIdx.x * 256 + t;
        if (i < 2 * SLEN) biasE[i] = -1.442695041e9f * (float)mask[i];
        return;
    }
    const float* W = (z == 0) ? w_v : (z == 1) ? w_k : (z == 2) ? w_q : w_o;
    unsigned short* Wt = (z == 0) ? WtV : (z == 1) ? WtK : (z == 2) ? WtQ : WtO;
    __shared__ float tile[64][65];
    const int tk = blockIdx.x / 12, tn = blockIdx.x % 12;
    const int k0 = tk * 64, n0 = tn * 64;
#pragma unroll
    for (int i = 0; i < 4; ++i) {
        int uid = t + 256 * i;
        int r = uid >> 4, c = (uid & 15) * 4;
        float4 v4 = *reinterpret_cast<const float4*>(W + (size_t)(k0 + r) * DH + n0 + c);
        tile[r][c] = v4.x; tile[r][c + 1] = v4.y; tile[r][c + 2] = v4.z; tile[r][c + 3] = v4.w;
    }
    __syncthreads();
#pragma unroll
    for (int i = 0; i < 2; ++i) {
        int uid = t + 256 * i;
        int n = uid >> 3, c = (uid & 7) * 8;
        union { unsigned short us[8]; uint4 u; } pk;
#pragma unroll
        for (int j = 0; j < 8; ++j) pk.us[j] = f2b(tile[c + j][n]);
        *reinterpret_cast<uint4*>(Wt + (size_t)(n0 + n) * DH + k0 + c) = pk.u;
    }
}

// ---- fused QKV projection, BN=128 (head pair). z=0: V -> VhT (pre-transposed). z=1: K. z=2: Q (pre-scaled) ----
__global__ __launch_bounds__(256) void proj3(const float* __restrict__ vin, const float* __restrict__ kin,
                                             const float* __restrict__ qin,
                                             const unsigned short* __restrict__ WtV,
                                             const unsigned short* __restrict__ WtK,
                                             const unsigned short* __restrict__ WtQ,
                                             unsigned short* __restrict__ VhT,
                                             unsigned short* __restrict__ Kh,
                                             unsigned short* __restrict__ Qh) {
    __shared__ unsigned char shraw[20480];
    unsigned short (*As)[40] = reinterpret_cast<unsigned short(*)[40]>(shraw);          // 128x32 (+8 pad)
    unsigned short (*Bs)[40] = reinterpret_cast<unsigned short(*)[40]>(shraw + 10240);  // 128x32 (+8 pad)
    const int t = threadIdx.x;
    const int w = t >> 6, lane = t & 63, lr = lane & 15, lg = lane >> 4;
    const int zz = blockIdx.y;
    const int z = zz / 6, hp = zz % 6;          // z: input select, hp: head pair
    const float* X = (z == 0) ? vin : (z == 1) ? kin : qin;
    const unsigned short* Wt = (z == 0) ? WtV : (z == 1) ? WtK : WtQ;
    const int row0 = blockIdx.x * 128;
    const int n0 = hp * 128;
    f32x4 acc[2][8] = {};
    for (int kt = 0; kt < 24; ++kt) {
        const int k0 = kt * 32;
#pragma unroll
        for (int i = 0; i < 4; ++i) {   // stage A: fp32 -> bf16, 128x32
            int r = (t >> 3) + 32 * i;
            int c = (t & 7) * 4;
            float4 v4 = *reinterpret_cast<const float4*>(X + (size_t)(row0 + r) * DH + k0 + c);
            uint2 pk;
            pk.x = pkbf(v4.x, v4.y);
            pk.y = pkbf(v4.z, v4.w);
            *reinterpret_cast<uint2*>(&As[r][c]) = pk;
        }
#pragma unroll
        for (int i = 0; i < 2; ++i) {   // stage B: 128x32 bf16
            int uid = t + 256 * i;
            int n = uid >> 2, c = (uid & 3) * 8;
            *reinterpret_cast<uint4*>(&Bs[n][c]) =
                *reinterpret_cast<const uint4*>(Wt + (size_t)(n0 + n) * DH + k0 + c);
        }
        __syncthreads();
        short8 af[2], bf[8];
#pragma unroll
        for (int mi = 0; mi < 2; ++mi)
            af[mi] = *reinterpret_cast<const short8*>(&As[w * 32 + mi * 16 + lr][lg * 8]);
#pragma unroll
        for (int ni = 0; ni < 8; ++ni)
            bf[ni] = *reinterpret_cast<const short8*>(&Bs[ni * 16 + lr][lg * 8]);
#pragma unroll
        for (int mi = 0; mi < 2; ++mi)
#pragma unroll
            for (int ni = 0; ni < 8; ++ni)
                acc[mi][ni] = __builtin_amdgcn_mfma_f32_16x16x32_bf16(af[mi], bf[ni], acc[mi][ni], 0, 0, 0);
        __syncthreads();
    }
    const int b = row0 >> 12, s0 = row0 & 4095;
    if (z == 0) {
        // V: per head, bounce through LDS to write VhT[bh][d][s] coalesced along s
        unsigned short (*Vt_e)[136] = reinterpret_cast<unsigned short(*)[136]>(shraw);
#pragma unroll
        for (int hh = 0; hh < 2; ++hh) {
            __syncthreads();
#pragma unroll
            for (int mi = 0; mi < 2; ++mi)
#pragma unroll
                for (int nn = 0; nn < 4; ++nn) {
                    int ni = hh * 4 + nn;
                    int d = nn * 16 + lr, sl = w * 32 + mi * 16 + lg * 4;
                    *reinterpret_cast<unsigned*>(&Vt_e[d][sl])     = pkbf(acc[mi][ni][0], acc[mi][ni][1]);
                    *reinterpret_cast<unsigned*>(&Vt_e[d][sl + 2]) = pkbf(acc[mi][ni][2], acc[mi][ni][3]);
                }
            __syncthreads();
            int d = t >> 2, sc = (t & 3) * 32;
            unsigned short* dst = VhT + ((size_t)(b * NHEAD + 2 * hp + hh) * DA + d) * SLEN + s0 + sc;
#pragma unroll
            for (int c = 0; c < 4; ++c)
                *reinterpret_cast<uint4*>(dst + c * 8) = *reinterpret_cast<const uint4*>(&Vt_e[d][sc + c * 8]);
        }
    } else {
        unsigned short* Y = (z == 1) ? Kh : Qh;
        const float scale = (z == 2) ? CSCALE : 1.0f;
#pragma unroll
        for (int mi = 0; mi < 2; ++mi)
#pragma unroll
            for (int ni = 0; ni < 8; ++ni)
#pragma unroll
                for (int r = 0; r < 4; ++r) {
                    int s = s0 + w * 32 + mi * 16 + lg * 4 + r;
                    int h = 2 * hp + (ni >> 2);
                    int d = (ni & 3) * 16 + lr;
                    Y[(size_t)((b * NHEAD + h) * SLEN + s) * DA + d] = f2b(acc[mi][ni][r] * scale);
                }
    }
}

// ---------------- flash attention: QBLK=128, ring-3 LDS, fixed-m softmax ----------------
// m = 0 fixed: P = 2^st directly. Safe: |st_unmasked| <= 0.18*|q||k| ~ 36 << 128 (fp32 exp range);
// masked st = -1.44e9 -> 2^x = 0 exactly. Scale cancels in O/l; bf16 rel-precision is scale-free.
__global__ __launch_bounds__(256, 3) void attn_kernel(const unsigned short* __restrict__ Qh,
                                                      const unsigned short* __restrict__ Kh,
                                                      const unsigned short* __restrict__ VhT,
                                                      const float* __restrict__ biasE,
                                                      unsigned short* __restrict__ AT) {
    __shared__ __align__(16) char smem[49152];   // 3 x (K 8KB + V 8KB); epilogue reuse at +16384
    const int t = threadIdx.x;
    const int w = t >> 6, lane = t & 63, lr = lane & 15, lg = lane >> 4;
    const int g0 = (lane >> 4) & 1, g1 = (lane >> 5) & 1;
    const int lr7 = lr & 7;

    // bijective XCD swizzle: 3 heads per XCD, all 32 q-blocks of a head on one XCD
    const int i = blockIdx.x;          // 0..767
    const int bh = (i & 7) * 3 + ((i >> 3) >> 5);
    const int qb = (i >> 3) & 31;
    const int b = bh / NHEAD;
    const int q0 = qb * 128;
    const size_t base = (size_t)bh * SLEN * DA;
    const int wq0 = q0 + w * 32;

    short8 qf[2][2];
#pragma unroll
    for (int mi = 0; mi < 2; ++mi)
#pragma unroll
        for (int ks = 0; ks < 2; ++ks)
            qf[mi][ks] = *reinterpret_cast<const short8*>(
                Qh + base + (size_t)(wq0 + mi * 16 + lr) * DA + ks * 32 + lg * 8);

    // staging source (pre-XOR-swizzled global, linear LDS dest); advance by one tile per STAGE
    const int uid0 = (w << 6) | lane;
    const int r0 = uid0 >> 3;
    const int sc0 = ((uid0 & 7) ^ (r0 & 7)) * 8;
    const unsigned short* kp = Kh + base + (size_t)r0 * DA + sc0;
    const unsigned short* vp = VhT + ((size_t)bh * DA + r0) * SLEN + sc0;
    const float* bp = biasE + b * SLEN + lg * 4;

    // ds_read lane addresses (byte offsets within a buffer); all reads use imm offsets off these
    const int a0 = lr * 128 + ((lg) ^ lr7) * 16;
    const int a1 = lr * 128 + ((4 + lg) ^ lr7) * 16;

    f32x4 st[2][4];
    f32x4 oacc[2][4] = {};
    f32x4 oacc_l[2] = {};
    f32x4 bias_c[4];
    short8 pa[2][2];
    union { unsigned u[4]; short8 s; } ones;
    ones.u[0] = 0x3F803F80u; ones.u[1] = 0x3F803F80u; ones.u[2] = 0x3F803F80u; ones.u[3] = 0x3F803F80u;

#define STAGE(CB) do {                                                   \
        GLD_LDS16(kp,              smem + (CB) + w * 1024);              \
        GLD_LDS16(kp + 2048,       smem + (CB) + (4 + w) * 1024);        \
        GLD_LDS16(vp,              smem + (CB) + 8192 + w * 1024);       \
        GLD_LDS16(vp + 32 * SLEN,  smem + (CB) + 8192 + (4 + w) * 1024); \
        kp += 64 * DA; vp += 64;                                         \
    } while (0)

#define BIASLD do {                                                              \
        _Pragma("unroll") for (int ni = 0; ni < 4; ++ni)                         \
            bias_c[ni] = *reinterpret_cast<const f32x4*>(bp + ni * 16);          \
        bp += 64;                                                                \
    } while (0)

#define QKT(NB) do {                                                                           \
        _Pragma("unroll") for (int ni = 0; ni < 4; ++ni) {                                     \
            short8 kf0 = *reinterpret_cast<const short8*>(smem + (NB) + ni * 2048 + a0);       \
            short8 kf1 = *reinterpret_cast<const short8*>(smem + (NB) + ni * 2048 + a1);       \
            st[0][ni] = __builtin_amdgcn_mfma_f32_16x16x32_bf16(kf1, qf[0][1],                 \
                        __builtin_amdgcn_mfma_f32_16x16x32_bf16(kf0, qf[0][0], bias_c[ni], 0, 0, 0), 0, 0, 0); \
            st[1][ni] = __builtin_amdgcn_mfma_f32_16x16x32_bf16(kf1, qf[1][1],                 \
                        __builtin_amdgcn_mfma_f32_16x16x32_bf16(kf0, qf[1][0], bias_c[ni], 0, 0, 0), 0, 0, 0); \
        }                                                                                      \
    } while (0)

#define PV(CB) do {                                                                                  \
        _Pragma("unroll") for (int ni = 0; ni < 4; ++ni) {                                           \
            short8 vf0 = *reinterpret_cast<const short8*>(smem + (CB) + 8192 + ni * 2048 + a0);      \
            short8 vf1 = *reinterpret_cast<const short8*>(smem + (CB) + 8192 + ni * 2048 + a1);      \
            oacc[0][ni] = __builtin_amdgcn_mfma_f32_16x16x32_bf16(vf0, pa[0][0], oacc[0][ni], 0, 0, 0); \
            oacc[0][ni] = __builtin_amdgcn_mfma_f32_16x16x32_bf16(vf1, pa[0][1], oacc[0][ni], 0, 0, 0); \
            oacc[1][ni] = __builtin_amdgcn_mfma_f32_16x16x32_bf16(vf0, pa[1][0], oacc[1][ni], 0, 0, 0); \
            oacc[1][ni] = __builtin_amdgcn_mfma_f32_16x16x32_bf16(vf1, pa[1][1], oacc[1][ni], 0, 0, 0); \
        }                                                                                            \
        oacc_l[0] = __builtin_amdgcn_mfma_f32_16x16x32_bf16(ones.s, pa[0][0], oacc_l[0], 0, 0, 0);   \
        oacc_l[0] = __builtin_amdgcn_mfma_f32_16x16x32_bf16(ones.s, pa[0][1], oacc_l[0], 0, 0, 0);   \
        oacc_l[1] = __builtin_amdgcn_mfma_f32_16x16x32_bf16(ones.s, pa[1][0], oacc_l[1], 0, 0, 0);   \
        oacc_l[1] = __builtin_amdgcn_mfma_f32_16x16x32_bf16(ones.s, pa[1][1], oacc_l[1], 0, 0, 0);   \
    } while (0)

// fixed-m softmax: P = 2^st, pack to bf16, permlane-transpose into PV A-frag layout
#define SOFTMAX do {                                                                               \
        _Pragma("unroll") for (int mi = 0; mi < 2; ++mi) {                                         \
            unsigned D[8];                                                                         \
            _Pragma("unroll") for (int ni = 0; ni < 4; ++ni) {                                     \
                float p0 = fexp2(st[mi][ni][0]);                                                   \
                float p1 = fexp2(st[mi][ni][1]);                                                   \
                float p2 = fexp2(st[mi][ni][2]);                                                   \
                float p3 = fexp2(st[mi][ni][3]);                                                   \
                D[ni * 2] = pkbf(p0, p1);                                                          \
                D[ni * 2 + 1] = pkbf(p2, p3);                                                      \
            }                                                                                      \
            swap32(D[0], D[2], g1); swap32(D[1], D[3], g1);                                        \
            swap32(D[4], D[6], g1); swap32(D[5], D[7], g1);                                        \
            swap16(D[0], D[2], g0); swap16(D[1], D[3], g0);                                        \
            swap16(D[4], D[6], g0); swap16(D[5], D[7], g0);                                        \
            union { unsigned u[4]; short8 s; } c0, c1;                                             \
            c0.u[0] = D[0]; c0.u[1] = D[1]; c0.u[2] = D[2]; c0.u[3] = D[3];                        \
            c1.u[0] = D[4]; c1.u[1] = D[5]; c1.u[2] = D[6]; c1.u[3] = D[7];                        \
            pa[mi][0] = c0.s; pa[mi][1] = c1.s;                                                    \
        }                                                                                          \
    } while (0)

#define BODY(KT, CB, NB, NNB) do {                                       \
        BIASLD;                        /* bias for tile KT+1 */          \
        SOFTMAX;                                                         \
        __syncthreads();                                                 \
        if ((KT) < 62) STAGE(NNB);                                       \
        __builtin_amdgcn_s_setprio(1);                                   \
        QKT(NB);                                                         \
        PV(CB);                                                          \
        __builtin_amdgcn_s_setprio(0);                                   \
    } while (0)

    // prologue: tiles 0,1 staged; bias(0); QK^T(0)
    STAGE(0);
    __syncthreads();
    BIASLD;
    STAGE(16384);
    __builtin_amdgcn_s_setprio(1);
    QKT(0);
    __builtin_amdgcn_s_setprio(0);

    for (int it = 0; it < 21; ++it) {
        BODY(3 * it,     0,     16384, 32768);
        BODY(3 * it + 1, 16384, 32768, 0);
        BODY(3 * it + 2, 32768, 0,     16384);
    }
    // final tile kt=63 (in buffer 0): no stage, no next-QKT
    SOFTMAX;
    __syncthreads();
    __builtin_amdgcn_s_setprio(1);
    PV(0);
    __builtin_amdgcn_s_setprio(0);

#undef BODY
#undef SOFTMAX
#undef PV
#undef QKT
#undef BIASLD
#undef STAGE

    // epilogue: l from ones-row accumulator (all entries equal), LDS bounce, coalesced store
    {
        float inv[2];
        inv[0] = 1.0f / oacc_l[0][0];
        inv[1] = 1.0f / oacc_l[1][0];
        unsigned* Obw = reinterpret_cast<unsigned*>(smem + 16384) + w * (32 * 36);
#pragma unroll
        for (int mi = 0; mi < 2; ++mi)
#pragma unroll
            for (int ni = 0; ni < 4; ++ni) {
                uint2 pr;
                pr.x = pkbf(oacc[mi][ni][0] * inv[mi], oacc[mi][ni][1] * inv[mi]);
                pr.y = pkbf(oacc[mi][ni][2] * inv[mi], oacc[mi][ni][3] * inv[mi]);
                *reinterpret_cast<uint2*>(&Obw[(mi * 16 + lr) * 36 + ni * 8 + lg * 2]) = pr;
            }
        __syncthreads();
        int row = lane >> 1, half = lane & 1;
        int qg = q0 + w * 32 + row;
        unsigned short* dst = AT + (size_t)(b * SLEN + qg) * DH + (bh % NHEAD) * DA + half * 32;
#pragma unroll
        for (int c = 0; c < 4; ++c) {
            uint4 v = *reinterpret_cast<const uint4*>(&Obw[row * 36 + half * 16 + c * 4]);
            *reinterpret_cast<uint4*>(dst + c * 8) = v;
        }
    }
}

// ---------------- output projection, BN=128: out(fp32) = AT(bf16) @ Wt_o^T + b_o ----
__global__ __launch_bounds__(256) void proj_out(const unsigned short* __restrict__ X,
                                                const unsigned short* __restrict__ Wt,
                                                const float* __restrict__ bias,
                                                float* __restrict__ Y) {
    __shared__ unsigned short As[128][40];
    __shared__ unsigned short Bs[128][40];
    const int t = threadIdx.x;
    const int w = t >> 6, lane = t & 63, lr = lane & 15, lg = lane >> 4;
    const int row0 = blockIdx.x * 128;
    const int n0 = blockIdx.y * 128;
    f32x4 acc[2][8] = {};
    for (int kt = 0; kt < 24; ++kt) {
        const int k0 = kt * 32;
#pragma unroll
        for (int i = 0; i < 2; ++i) {
            int uid = t + 256 * i;
            int r = uid >> 2, c = (uid & 3) * 8;
            *reinterpret_cast<uint4*>(&As[r][c]) =
                *reinterpret_cast<const uint4*>(X + (size_t)(row0 + r) * DH + k0 + c);
        }
#pragma unroll
        for (int i = 0; i < 2; ++i) {
            int uid = t + 256 * i;
            int n = uid >> 2, c = (uid & 3) * 8;
            *reinterpret_cast<uint4*>(&Bs[n][c]) =
                *reinterpret_cast<const uint4*>(Wt + (size_t)(n0 + n) * DH + k0 + c);
        }
        __syncthreads();
        short8 af[2], bf[8];
#pragma unroll
        for (int mi = 0; mi < 2; ++mi)
            af[mi] = *reinterpret_cast<const short8*>(&As[w * 32 + mi * 16 + lr][lg * 8]);
#pragma unroll
        for (int ni = 0; ni < 8; ++ni)
            bf[ni] = *reinterpret_cast<const short8*>(&Bs[ni * 16 + lr][lg * 8]);
#pragma unroll
        for (int mi = 0; mi < 2; ++mi)
#pragma unroll
            for (int ni = 0; ni < 8; ++ni)
                acc[mi][ni] = __builtin_amdgcn_mfma_f32_16x16x32_bf16(af[mi], bf[ni], acc[mi][ni], 0, 0, 0);
        __syncthreads();
    }
#pragma unroll
    for (int ni = 0; ni < 8; ++ni) {
        float bv = bias[n0 + ni * 16 + lr];
#pragma unroll
        for (int mi = 0; mi < 2; ++mi)
#pragma unroll
            for (int r = 0; r < 4; ++r) {
                int row = row0 + w * 32 + mi * 16 + lg * 4 + r;
                Y[(size_t)row * DH + n0 + ni * 16 + lr] = acc[mi][ni][r] + bv;
            }
    }
}

extern "C" void kernel_launch(void* const* d_in, const int* in_sizes, int n_in,
                              void* d_out, int out_size, void* d_ws, size_t ws_size,
                              hipStream_t stream) {
    const float* v   = (const float*)d_in[0];
    const float* k   = (const float*)d_in[1];
    const float* q   = (const float*)d_in[2];
    const int*  mask = (const int*)d_in[3];
    const float* w_v = (const float*)d_in[4];
    const float* w_k = (const float*)d_in[5];
    const float* w_q = (const float*)d_in[6];
    const float* w_o = (const float*)d_in[7];
    const float* b_o = (const float*)d_in[8];
    float* out = (float*)d_out;

    char* ws = (char*)d_ws;
    unsigned short* Qh  = (unsigned short*)(ws);                 // 12.58 MB
    unsigned short* Kh  = (unsigned short*)(ws + 12582912);
    unsigned short* AT  = (unsigned short*)(ws + 25165824);
    unsigned short* VhT = (unsigned short*)(ws + 37748736);
    unsigned short* WtV = (unsigned short*)(ws + 50331648);
    unsigned short* WtK = WtV + 589824;
    unsigned short* WtQ = WtK + 589824;
    unsigned short* WtO = WtQ + 589824;
    float* biasE = (float*)(ws + 55050240);                      // 32 KB

    wtrans4<<<dim3(144, 5), 256, 0, stream>>>(w_v, w_k, w_q, w_o, WtV, WtK, WtQ, WtO, mask, biasE);
    proj3<<<dim3(64, 18), 256, 0, stream>>>(v, k, q, WtV, WtK, WtQ, VhT, Kh, Qh);
    attn_kernel<<<768, 256, 0, stream>>>(Qh, Kh, VhT, biasE, AT);
    proj_out<<<dim3(64, 6), 256, 0, stream>>>(AT, WtO, b_o, out);
}

// Round 7
// 170.229 us; speedup vs baseline: 1.5858x; 1.3379x over previous
//
#include <hip/hip_runtime.h>
#include <hip/hip_bf16.h>

#define SLEN 4096
#define DH 768
#define NHEAD 12
#define DA 64

using short8 = __attribute__((ext_vector_type(8))) short;
using f32x4  = __attribute__((ext_vector_type(4))) float;
typedef unsigned uv2 __attribute__((ext_vector_type(2)));

static __device__ __forceinline__ unsigned short f2b(float f) {
    union { __hip_bfloat16 h; unsigned short u; } c;
    c.h = __float2bfloat16(f);
    return c.u;
}

static __device__ __forceinline__ unsigned pkbf(float a, float b) {
    __hip_bfloat162 h = __float22bfloat162_rn(float2{a, b});
    union { __hip_bfloat162 h; unsigned u; } c; c.h = h; return c.u;
}

// native 2^x — single v_exp_f32, no libcall fallback
static __device__ __forceinline__ float fexp2(float x) {
    float r; asm("v_exp_f32 %0, %1" : "=v"(r) : "v"(x)); return r;
}

// {a,b} -> a'={a.lo,b.lo}, b'={a.hi,b.hi}  (swap across lane^32)
static __device__ __forceinline__ void swap32(unsigned& a, unsigned& b, int g1) {
#if __has_builtin(__builtin_amdgcn_permlane32_swap)
    uv2 r = __builtin_amdgcn_permlane32_swap(a, b, false, false);
    a = r.x; b = r.y;
#else
    unsigned own = g1 ? b : a, send = g1 ? a : b;
    unsigned recv = __shfl_xor(send, 32);
    unsigned nlo = g1 ? recv : own;
    unsigned nhi = g1 ? own : recv;
    a = nlo; b = nhi;
#endif
}

// {a,b} -> a'={a.q0,b.q0,a.q2,b.q2}, b'={a.q1,b.q1,a.q3,b.q3}  (swap across lane^16)
static __device__ __forceinline__ void swap16(unsigned& a, unsigned& b, int g0) {
#if __has_builtin(__builtin_amdgcn_permlane16_swap)
    uv2 r = __builtin_amdgcn_permlane16_swap(a, b, false, false);
    a = r.x; b = r.y;
#else
    unsigned own = g0 ? b : a, send = g0 ? a : b;
    unsigned recv = __shfl_xor(send, 16);
    unsigned nlo = g0 ? recv : own;
    unsigned nhi = g0 ? own : recv;
    a = nlo; b = nhi;
#endif
}

#define GLD_LDS16(gp, lp) __builtin_amdgcn_global_load_lds( \
    (const __attribute__((address_space(1))) unsigned int*)(gp), \
    (__attribute__((address_space(3))) unsigned int*)(lp), 16, 0, 0)

#define CSCALE 0.18033688011f   // 0.125 * log2(e)
#define BIASSTRIDE 4352

// ------- 4x weight transpose + bf16 convert: Wt[n][k] = bf16(W[k][n]) -------
__global__ __launch_bounds__(256) void wtrans4(const float* __restrict__ w_v, const float* __restrict__ w_k,
                                               const float* __restrict__ w_q, const float* __restrict__ w_o,
                                               unsigned short* __restrict__ WtV, unsigned short* __restrict__ WtK,
                                               unsigned short* __restrict__ WtQ, unsigned short* __restrict__ WtO) {
    const int z = blockIdx.y;
    const int t = threadIdx.x;
    const float* W = (z == 0) ? w_v : (z == 1) ? w_k : (z == 2) ? w_q : w_o;
    unsigned short* Wt = (z == 0) ? WtV : (z == 1) ? WtK : (z == 2) ? WtQ : WtO;
    __shared__ float tile[64][65];
    const int tk = blockIdx.x / 12, tn = blockIdx.x % 12;
    const int k0 = tk * 64, n0 = tn * 64;
#pragma unroll
    for (int i = 0; i < 4; ++i) {
        int uid = t + 256 * i;
        int r = uid >> 4, c = (uid & 15) * 4;
        float4 v4 = *reinterpret_cast<const float4*>(W + (size_t)(k0 + r) * DH + n0 + c);
        tile[r][c] = v4.x; tile[r][c + 1] = v4.y; tile[r][c + 2] = v4.z; tile[r][c + 3] = v4.w;
    }
    __syncthreads();
#pragma unroll
    for (int i = 0; i < 2; ++i) {
        int uid = t + 256 * i;
        int n = uid >> 3, c = (uid & 7) * 8;
        union { unsigned short us[8]; uint4 u; } pk;
#pragma unroll
        for (int j = 0; j < 8; ++j) pk.us[j] = f2b(tile[c + j][n]);
        *reinterpret_cast<uint4*>(Wt + (size_t)(n0 + n) * DH + k0 + c) = pk.u;
    }
}

// ------- mask compaction scan: per batch, list of kept (mask==0) key indices -------
// idx[b][j] = s of j-th kept key (0 for pad); biasC[b][j] = 0 kept / -1.44e9 pad; nktArr[b] = ceil(nkept/64)
__global__ __launch_bounds__(256) void maskscan(const int* __restrict__ mask,
                                                int* __restrict__ idx,
                                                float* __restrict__ biasC,
                                                int* __restrict__ nktArr) {
    __shared__ int psum[256];
    const int b = blockIdx.x;
    const int t = threadIdx.x;
    const int s0 = t * 16;
    const int* mb = mask + b * SLEN;
    int keep[16]; int cnt = 0;
#pragma unroll
    for (int j = 0; j < 16; ++j) { keep[j] = (mb[s0 + j] == 0); cnt += keep[j]; }
    psum[t] = cnt;
    __syncthreads();
    for (int off = 1; off < 256; off <<= 1) {
        int v = psum[t];
        int u = (t >= off) ? psum[t - off] : 0;
        __syncthreads();
        psum[t] = v + u;
        __syncthreads();
    }
    int excl = psum[t] - cnt;
    int total = psum[255];
    int* ib = idx + b * SLEN;
#pragma unroll
    for (int j = 0; j < 16; ++j)
        if (keep[j]) ib[excl++] = s0 + j;
    for (int j = total + t; j < SLEN; j += 256) ib[j] = 0;
    int nkt = (total + 63) >> 6;
    if (nkt < 2) nkt = 2;
    if (t == 0) nktArr[b] = nkt;
    float* bb = biasC + b * BIASSTRIDE;
    for (int j = t; j < BIASSTRIDE; j += 256) bb[j] = (j < total) ? 0.f : -1.442695041e9f;
}

// ---- fused QKV projection (BN=64). z=0: V->VhT compacted+transposed. z=1: K compacted. z=2: Q full, pre-scaled ----
__global__ __launch_bounds__(256) void proj3(const float* __restrict__ vin, const float* __restrict__ kin,
                                             const float* __restrict__ qin,
                                             const unsigned short* __restrict__ WtV,
                                             const unsigned short* __restrict__ WtK,
                                             const unsigned short* __restrict__ WtQ,
                                             unsigned short* __restrict__ VhT,
                                             unsigned short* __restrict__ Kh,
                                             unsigned short* __restrict__ Qh,
                                             const int* __restrict__ idx,
                                             const int* __restrict__ nktArr) {
    __shared__ unsigned char shraw[17408];
    unsigned short (*As)[40] = reinterpret_cast<unsigned short(*)[40]>(shraw);          // 128x32 (+8 pad)
    unsigned short (*Bs)[40] = reinterpret_cast<unsigned short(*)[40]>(shraw + 10240);  // 64x32 (+8 pad)
    const int t = threadIdx.x;
    const int w = t >> 6, lane = t & 63, lr = lane & 15, lg = lane >> 4;
    const int zz = blockIdx.y;
    const int z = zz / 12, h = zz % 12;
    const float* X = (z == 0) ? vin : (z == 1) ? kin : qin;
    const unsigned short* Wt = (z == 0) ? WtV : (z == 1) ? WtK : WtQ;
    const int b = blockIdx.x >> 5;
    const int j0 = (blockIdx.x & 31) * 128;       // compact row base (or s base for Q)
    const bool gather = (z != 2);
    if (gather && j0 >= nktArr[b] * 64) return;   // fully-pad block: rows never read by attn
    const int n0 = h * 64;
    // source rows for this thread's 4 A-stage loads
    int grow[4];
#pragma unroll
    for (int i = 0; i < 4; ++i) {
        int r = (t >> 3) + 32 * i;
        grow[i] = b * SLEN + (gather ? idx[b * SLEN + j0 + r] : (j0 + r));
    }
    f32x4 acc[2][4] = {};
    for (int kt = 0; kt < 24; ++kt) {
        const int k0 = kt * 32;
#pragma unroll
        for (int i = 0; i < 4; ++i) {
            int r = (t >> 3) + 32 * i;
            int c = (t & 7) * 4;
            float4 v4 = *reinterpret_cast<const float4*>(X + (size_t)grow[i] * DH + k0 + c);
            uint2 pk;
            pk.x = pkbf(v4.x, v4.y);
            pk.y = pkbf(v4.z, v4.w);
            *reinterpret_cast<uint2*>(&As[r][c]) = pk;
        }
        {
            int n = t >> 2, c = (t & 3) * 8;
            *reinterpret_cast<uint4*>(&Bs[n][c]) =
                *reinterpret_cast<const uint4*>(Wt + (size_t)(n0 + n) * DH + k0 + c);
        }
        __syncthreads();
        short8 af[2], bf[4];
#pragma unroll
        for (int mi = 0; mi < 2; ++mi)
            af[mi] = *reinterpret_cast<const short8*>(&As[w * 32 + mi * 16 + lr][lg * 8]);
#pragma unroll
        for (int ni = 0; ni < 4; ++ni)
            bf[ni] = *reinterpret_cast<const short8*>(&Bs[ni * 16 + lr][lg * 8]);
#pragma unroll
        for (int mi = 0; mi < 2; ++mi)
#pragma unroll
            for (int ni = 0; ni < 4; ++ni)
                acc[mi][ni] = __builtin_amdgcn_mfma_f32_16x16x32_bf16(af[mi], bf[ni], acc[mi][ni], 0, 0, 0);
        __syncthreads();
    }
    if (z == 0) {
        // V: bounce through LDS to write VhT[bh][d][j] coalesced along compact j
        unsigned short (*Vt_e)[136] = reinterpret_cast<unsigned short(*)[136]>(shraw);
#pragma unroll
        for (int mi = 0; mi < 2; ++mi)
#pragma unroll
            for (int ni = 0; ni < 4; ++ni) {
                int d = ni * 16 + lr, sl = w * 32 + mi * 16 + lg * 4;
                *reinterpret_cast<unsigned*>(&Vt_e[d][sl])     = pkbf(acc[mi][ni][0], acc[mi][ni][1]);
                *reinterpret_cast<unsigned*>(&Vt_e[d][sl + 2]) = pkbf(acc[mi][ni][2], acc[mi][ni][3]);
            }
        __syncthreads();
        int d = t >> 2, sc = (t & 3) * 32;
        unsigned short* dst = VhT + ((size_t)(b * NHEAD + h) * DA + d) * SLEN + j0 + sc;
#pragma unroll
        for (int c = 0; c < 4; ++c)
            *reinterpret_cast<uint4*>(dst + c * 8) = *reinterpret_cast<const uint4*>(&Vt_e[d][sc + c * 8]);
    } else {
        unsigned short* Y = (z == 1) ? Kh : Qh;
        const float scale = (z == 2) ? CSCALE : 1.0f;
#pragma unroll
        for (int mi = 0; mi < 2; ++mi)
#pragma unroll
            for (int ni = 0; ni < 4; ++ni)
#pragma unroll
                for (int r = 0; r < 4; ++r) {
                    int j = j0 + w * 32 + mi * 16 + lg * 4 + r;
                    int d = ni * 16 + lr;
                    Y[(size_t)((b * NHEAD + h) * SLEN + j) * DA + d] = f2b(acc[mi][ni][r] * scale);
                }
    }
}

// ---------------- flash attention: QBLK=128, ring-3 LDS, fixed-m, compacted keys ----------------
// m = 0 fixed: P = 2^st. Kept keys have bias 0 (in MFMA C); pad keys bias -1.44e9 -> p = 0 exactly.
__global__ __launch_bounds__(256, 3) void attn_kernel(const unsigned short* __restrict__ Qh,
                                                      const unsigned short* __restrict__ Kh,
                                                      const unsigned short* __restrict__ VhT,
                                                      const float* __restrict__ biasC,
                                                      const int* __restrict__ nktArr,
                                                      unsigned short* __restrict__ AT) {
    __shared__ __align__(16) char smem[49152];   // 3 x (K 8KB + V 8KB)
    const int t = threadIdx.x;
    const int w = t >> 6, lane = t & 63, lr = lane & 15, lg = lane >> 4;
    const int g0 = (lane >> 4) & 1, g1 = (lane >> 5) & 1;
    const int lr7 = lr & 7;

    // bijective XCD swizzle: 3 heads per XCD, all 32 q-blocks of a head on one XCD
    const int i = blockIdx.x;          // 0..767
    const int bh = (i & 7) * 3 + ((i >> 3) >> 5);
    const int qb = (i >> 3) & 31;
    const int b = bh / NHEAD;
    const int q0 = qb * 128;
    const size_t base = (size_t)bh * SLEN * DA;
    const int wq0 = q0 + w * 32;
    const int nkt = nktArr[b];

    short8 qf[2][2];
#pragma unroll
    for (int mi = 0; mi < 2; ++mi)
#pragma unroll
        for (int ks = 0; ks < 2; ++ks)
            qf[mi][ks] = *reinterpret_cast<const short8*>(
                Qh + base + (size_t)(wq0 + mi * 16 + lr) * DA + ks * 32 + lg * 8);

    // staging source (pre-XOR-swizzled global, linear LDS dest); advance one tile per STAGE
    const int uid0 = (w << 6) | lane;
    const int r0 = uid0 >> 3;
    const int sc0 = ((uid0 & 7) ^ (r0 & 7)) * 8;
    const unsigned short* kp = Kh + base + (size_t)r0 * DA + sc0;
    const unsigned short* vp = VhT + ((size_t)bh * DA + r0) * SLEN + sc0;
    const float* bp = biasC + b * BIASSTRIDE + lg * 4;

    // ds_read lane addresses (byte offsets within a buffer)
    const int a0 = lr * 128 + ((lg) ^ lr7) * 16;
    const int a1 = lr * 128 + ((4 + lg) ^ lr7) * 16;

    f32x4 st[2][4];
    f32x4 oacc[2][4] = {};
    f32x4 oacc_l[2] = {};
    f32x4 bias_c[4];
    short8 pa[2][2];
    union { unsigned u[4]; short8 s; } ones;
    ones.u[0] = 0x3F803F80u; ones.u[1] = 0x3F803F80u; ones.u[2] = 0x3F803F80u; ones.u[3] = 0x3F803F80u;

#define STAGE(CB) do {                                                   \
        GLD_LDS16(kp,              smem + (CB) + w * 1024);              \
        GLD_LDS16(kp + 2048,       smem + (CB) + (4 + w) * 1024);        \
        GLD_LDS16(vp,              smem + (CB) + 8192 + w * 1024);       \
        GLD_LDS16(vp + 32 * SLEN,  smem + (CB) + 8192 + (4 + w) * 1024); \
        kp += 64 * DA; vp += 64;                                         \
    } while (0)

#define BIASLD do {                                                              \
        _Pragma("unroll") for (int ni = 0; ni < 4; ++ni)                         \
            bias_c[ni] = *reinterpret_cast<const f32x4*>(bp + ni * 16);          \
        bp += 64;                                                                \
    } while (0)

#define QKT(NB) do {                                                                           \
        _Pragma("unroll") for (int ni = 0; ni < 4; ++ni) {                                     \
            short8 kf0 = *reinterpret_cast<const short8*>(smem + (NB) + ni * 2048 + a0);       \
            short8 kf1 = *reinterpret_cast<const short8*>(smem + (NB) + ni * 2048 + a1);       \
            st[0][ni] = __builtin_amdgcn_mfma_f32_16x16x32_bf16(kf1, qf[0][1],                 \
                        __builtin_amdgcn_mfma_f32_16x16x32_bf16(kf0, qf[0][0], bias_c[ni], 0, 0, 0), 0, 0, 0); \
            st[1][ni] = __builtin_amdgcn_mfma_f32_16x16x32_bf16(kf1, qf[1][1],                 \
                        __builtin_amdgcn_mfma_f32_16x16x32_bf16(kf0, qf[1][0], bias_c[ni], 0, 0, 0), 0, 0, 0); \
        }                                                                                      \
    } while (0)

#define PV(CB) do {                                                                                  \
        _Pragma("unroll") for (int ni = 0; ni < 4; ++ni) {                                           \
            short8 vf0 = *reinterpret_cast<const short8*>(smem + (CB) + 8192 + ni * 2048 + a0);      \
            short8 vf1 = *reinterpret_cast<const short8*>(smem + (CB) + 8192 + ni * 2048 + a1);      \
            oacc[0][ni] = __builtin_amdgcn_mfma_f32_16x16x32_bf16(vf0, pa[0][0], oacc[0][ni], 0, 0, 0); \
            oacc[0][ni] = __builtin_amdgcn_mfma_f32_16x16x32_bf16(vf1, pa[0][1], oacc[0][ni], 0, 0, 0); \
            oacc[1][ni] = __builtin_amdgcn_mfma_f32_16x16x32_bf16(vf0, pa[1][0], oacc[1][ni], 0, 0, 0); \
            oacc[1][ni] = __builtin_amdgcn_mfma_f32_16x16x32_bf16(vf1, pa[1][1], oacc[1][ni], 0, 0, 0); \
        }                                                                                            \
        oacc_l[0] = __builtin_amdgcn_mfma_f32_16x16x32_bf16(ones.s, pa[0][0], oacc_l[0], 0, 0, 0);   \
        oacc_l[0] = __builtin_amdgcn_mfma_f32_16x16x32_bf16(ones.s, pa[0][1], oacc_l[0], 0, 0, 0);   \
        oacc_l[1] = __builtin_amdgcn_mfma_f32_16x16x32_bf16(ones.s, pa[1][0], oacc_l[1], 0, 0, 0);   \
        oacc_l[1] = __builtin_amdgcn_mfma_f32_16x16x32_bf16(ones.s, pa[1][1], oacc_l[1], 0, 0, 0);   \
    } while (0)

#define SOFTMAX do {                                                                               \
        _Pragma("unroll") for (int mi = 0; mi < 2; ++mi) {                                         \
            unsigned D[8];                                                                         \
            _Pragma("unroll") for (int ni = 0; ni < 4; ++ni) {                                     \
                float p0 = fexp2(st[mi][ni][0]);                                                   \
                float p1 = fexp2(st[mi][ni][1]);                                                   \
                float p2 = fexp2(st[mi][ni][2]);                                                   \
                float p3 = fexp2(st[mi][ni][3]);                                                   \
                D[ni * 2] = pkbf(p0, p1);                                                          \
                D[ni * 2 + 1] = pkbf(p2, p3);                                                      \
            }                                                                                      \
            swap32(D[0], D[2], g1); swap32(D[1], D[3], g1);                                        \
            swap32(D[4], D[6], g1); swap32(D[5], D[7], g1);                                        \
            swap16(D[0], D[2], g0); swap16(D[1], D[3], g0);                                        \
            swap16(D[4], D[6], g0); swap16(D[5], D[7], g0);                                        \
            union { unsigned u[4]; short8 s; } c0, c1;                                             \
            c0.u[0] = D[0]; c0.u[1] = D[1]; c0.u[2] = D[2]; c0.u[3] = D[3];                        \
            c1.u[0] = D[4]; c1.u[1] = D[5]; c1.u[2] = D[6]; c1.u[3] = D[7];                        \
            pa[mi][0] = c0.s; pa[mi][1] = c1.s;                                                    \
        }                                                                                          \
    } while (0)

    // prologue: tiles 0,1 staged; bias(0); QK^T(0)
    STAGE(0);
    __syncthreads();
    BIASLD;
    STAGE(16384);
    __builtin_amdgcn_s_setprio(1);
    QKT(0);
    __builtin_amdgcn_s_setprio(0);

    int cb = 0, nb = 16384, nnb = 32768;
    for (int kt = 0; kt < nkt - 1; ++kt) {
        BIASLD;                        // bias for tile kt+1
        SOFTMAX;                       // p of tile kt
        __syncthreads();
        if (kt < nkt - 2) STAGE(nnb);
        __builtin_amdgcn_s_setprio(1);
        QKT(nb);
        PV(cb);
        __builtin_amdgcn_s_setprio(0);
        int tmp = cb; cb = nb; nb = nnb; nnb = tmp;
    }
    // final tile
    SOFTMAX;
    __syncthreads();
    __builtin_amdgcn_s_setprio(1);
    PV(cb);
    __builtin_amdgcn_s_setprio(0);

#undef SOFTMAX
#undef PV
#undef QKT
#undef BIASLD
#undef STAGE

    // epilogue: barrier (final buffer is dynamic), l from ones-accumulator, LDS bounce, coalesced store
    {
        __syncthreads();
        float inv[2];
        inv[0] = 1.0f / oacc_l[0][0];
        inv[1] = 1.0f / oacc_l[1][0];
        unsigned* Obw = reinterpret_cast<unsigned*>(smem) + w * (32 * 36);
#pragma unroll
        for (int mi = 0; mi < 2; ++mi)
#pragma unroll
            for (int ni = 0; ni < 4; ++ni) {
                uint2 pr;
                pr.x = pkbf(oacc[mi][ni][0] * inv[mi], oacc[mi][ni][1] * inv[mi]);
                pr.y = pkbf(oacc[mi][ni][2] * inv[mi], oacc[mi][ni][3] * inv[mi]);
                *reinterpret_cast<uint2*>(&Obw[(mi * 16 + lr) * 36 + ni * 8 + lg * 2]) = pr;
            }
        __syncthreads();
        int row = lane >> 1, half = lane & 1;
        int qg = q0 + w * 32 + row;
        unsigned short* dst = AT + (size_t)(b * SLEN + qg) * DH + (bh % NHEAD) * DA + half * 32;
#pragma unroll
        for (int c = 0; c < 4; ++c) {
            uint4 v = *reinterpret_cast<const uint4*>(&Obw[row * 36 + half * 16 + c * 4]);
            *reinterpret_cast<uint4*>(dst + c * 8) = v;
        }
    }
}

// ---------------- output projection (BN=64): out(fp32) = AT(bf16) @ Wt_o^T + b_o ----
__global__ __launch_bounds__(256) void proj_out(const unsigned short* __restrict__ X,
                                                const unsigned short* __restrict__ Wt,
                                                const float* __restrict__ bias,
                                                float* __restrict__ Y) {
    __shared__ unsigned short As[128][40];
    __shared__ unsigned short Bs[64][40];
    const int t = threadIdx.x;
    const int w = t >> 6, lane = t & 63, lr = lane & 15, lg = lane >> 4;
    const int row0 = blockIdx.x * 128;
    const int n0 = blockIdx.y * 64;
    f32x4 acc[2][4] = {};
    for (int kt = 0; kt < 24; ++kt) {
        const int k0 = kt * 32;
#pragma unroll
        for (int i = 0; i < 2; ++i) {
            int uid = t + 256 * i;
            int r = uid >> 2, c = (uid & 3) * 8;
            *reinterpret_cast<uint4*>(&As[r][c]) =
                *reinterpret_cast<const uint4*>(X + (size_t)(row0 + r) * DH + k0 + c);
        }
        {
            int n = t >> 2, c = (t & 3) * 8;
            *reinterpret_cast<uint4*>(&Bs[n][c]) =
                *reinterpret_cast<const uint4*>(Wt + (size_t)(n0 + n) * DH + k0 + c);
        }
        __syncthreads();
        short8 af[2], bf[4];
#pragma unroll
        for (int mi = 0; mi < 2; ++mi)
            af[mi] = *reinterpret_cast<const short8*>(&As[w * 32 + mi * 16 + lr][lg * 8]);
#pragma unroll
        for (int ni = 0; ni < 4; ++ni)
            bf[ni] = *reinterpret_cast<const short8*>(&Bs[ni * 16 + lr][lg * 8]);
#pragma unroll
        for (int mi = 0; mi < 2; ++mi)
#pragma unroll
            for (int ni = 0; ni < 4; ++ni)
                acc[mi][ni] = __builtin_amdgcn_mfma_f32_16x16x32_bf16(af[mi], bf[ni], acc[mi][ni], 0, 0, 0);
        __syncthreads();
    }
#pragma unroll
    for (int ni = 0; ni < 4; ++ni) {
        float bv = bias[n0 + ni * 16 + lr];
#pragma unroll
        for (int mi = 0; mi < 2; ++mi)
#pragma unroll
            for (int r = 0; r < 4; ++r) {
                int row = row0 + w * 32 + mi * 16 + lg * 4 + r;
                Y[(size_t)row * DH + n0 + ni * 16 + lr] = acc[mi][ni][r] + bv;
            }
    }
}

extern "C" void kernel_launch(void* const* d_in, const int* in_sizes, int n_in,
                              void* d_out, int out_size, void* d_ws, size_t ws_size,
                              hipStream_t stream) {
    const float* v   = (const float*)d_in[0];
    const float* k   = (const float*)d_in[1];
    const float* q   = (const float*)d_in[2];
    const int*  mask = (const int*)d_in[3];
    const float* w_v = (const float*)d_in[4];
    const float* w_k = (const float*)d_in[5];
    const float* w_q = (const float*)d_in[6];
    const float* w_o = (const float*)d_in[7];
    const float* b_o = (const float*)d_in[8];
    float* out = (float*)d_out;

    char* ws = (char*)d_ws;
    unsigned short* Qh  = (unsigned short*)(ws);                 // 12.58 MB
    unsigned short* Khc = (unsigned short*)(ws + 12582912);      // compacted K
    unsigned short* AT  = (unsigned short*)(ws + 25165824);
    unsigned short* VhTc= (unsigned short*)(ws + 37748736);      // compacted V^T
    unsigned short* WtV = (unsigned short*)(ws + 50331648);
    unsigned short* WtK = WtV + 589824;
    unsigned short* WtQ = WtK + 589824;
    unsigned short* WtO = WtQ + 589824;
    float* biasC = (float*)(ws + 55050240);                      // 2 x 4352 f32
    int*   idxA  = (int*)(ws + 55085056);                        // 2 x 4096 int
    int*   nktA  = (int*)(ws + 55117824);                        // 2 int

    wtrans4<<<dim3(144, 4), 256, 0, stream>>>(w_v, w_k, w_q, w_o, WtV, WtK, WtQ, WtO);
    maskscan<<<2, 256, 0, stream>>>(mask, idxA, biasC, nktA);
    proj3<<<dim3(64, 36), 256, 0, stream>>>(v, k, q, WtV, WtK, WtQ, VhTc, Khc, Qh, idxA, nktA);
    attn_kernel<<<768, 256, 0, stream>>>(Qh, Khc, VhTc, biasC, nktA, AT);
    proj_out<<<dim3(64, 12), 256, 0, stream>>>(AT, WtO, b_o, out);
}